// Round 3
// baseline (410.446 us; speedup 1.0000x reference)
//
#include <hip/hip_runtime.h>
#include <hip/hip_bf16.h>

#define NATOMS 16384
#define MOLS   64
#define ATOMSM 256
#define EGB    524288
#define EGNN   262144
#define HID    128
#define NH     (NATOMS*HID)

#define OFFSETC 0.009f
#define ALPHAC  1.0f
#define BETAC   0.8f
#define GAMMAC  4.85f
#define PREFC   (-138.935456f*(1.0f-1.0f/78.5f))

typedef __hip_bfloat16 bf;
typedef __attribute__((ext_vector_type(8))) short bf8v;
typedef __attribute__((ext_vector_type(4))) float f4v;
typedef unsigned int uint;

__device__ __forceinline__ float b2f(bf x){ return __bfloat162float(x); }
__device__ __forceinline__ bf f2b(float x){ return __float2bfloat16(x); }
__device__ __forceinline__ short f2s(float x){ bf h = f2b(x); return *(short*)&h; }
__device__ __forceinline__ float s2f(short s){
    unsigned int x = ((unsigned int)(unsigned short)s) << 16;
    return __uint_as_float(x);
}
__device__ __forceinline__ float sigf(float x){ return 1.0f/(1.0f+__expf(-x)); }
__device__ __forceinline__ float waveRed(float v){
    v += __shfl_xor(v,32); v += __shfl_xor(v,16); v += __shfl_xor(v,8);
    v += __shfl_xor(v,4);  v += __shfl_xor(v,2);  v += __shfl_xor(v,1);
    return v;
}
__device__ __forceinline__ uint pack2(float a, float b){
    return (uint)(unsigned short)f2s(a) | ((uint)(unsigned short)f2s(b) << 16);
}
__device__ __forceinline__ float lo2f(uint w){ return __uint_as_float(w << 16); }
__device__ __forceinline__ float hi2f(uint w){ return __uint_as_float(w & 0xffff0000u); }

// ============ MEGA-A: weight prep + uv1 + gbA + gnn-dist ============
__global__ __launch_bounds__(256) void k_A(
    const float* __restrict__ A2, const float* __restrict__ C1,
    const float* __restrict__ A3, const float* __restrict__ C2,
    short* __restrict__ C1t, short* __restrict__ C2t,
    short* __restrict__ A2at, short* __restrict__ A2bt,
    short* __restrict__ A3at, short* __restrict__ A3bt,
    short* __restrict__ rA2a, short* __restrict__ rA2b,
    short* __restrict__ rA3a, short* __restrict__ rA3b,
    short* __restrict__ rC1, short* __restrict__ rC2,
    const float* __restrict__ feat, const float* __restrict__ A1,
    bf* __restrict__ u1, bf* __restrict__ v1,
    const float* __restrict__ pos, const int* __restrict__ ei,
    float* __restrict__ Isum,
    const int* __restrict__ gei, float* __restrict__ dgnn, int* __restrict__ cnt)
{
    int tid = threadIdx.x;
    if (blockIdx.x < 64){
        int gid = blockIdx.x*256 + tid;
        int j = gid >> 7, k = gid & 127;
        C1t[gid]  = f2s(C1[k*HID+j]);
        C2t[gid]  = f2s(C2[k*HID+j]);
        A2at[gid] = f2s(A2[k*HID+j]);
        A2bt[gid] = f2s(A2[(HID+k)*HID+j]);
        A3at[gid] = f2s(A3[k*HID+j]);
        A3bt[gid] = f2s(A3[(HID+k)*HID+j]);
        rA2a[gid] = f2s(A2[gid]);
        rA2b[gid] = f2s(A2[HID*HID+gid]);
        rA3a[gid] = f2s(A3[gid]);
        rA3b[gid] = f2s(A3[HID*HID+gid]);
        rC1[gid]  = f2s(C1[gid]);
        rC2[gid]  = f2s(C2[gid]);
    } else if (blockIdx.x < 4160){
        int gid2 = (blockIdx.x-64)*256 + tid;   // [0, NH/2)
        int i = gid2 >> 6, k2 = (gid2 & 63)*2;
        float q = feat[7*i+0], r = feat[7*i+1];
        float u0 = q*A1[k2]         + r*A1[HID+k2];
        float u1v= q*A1[k2+1]       + r*A1[HID+k2+1];
        float v0 = q*A1[2*HID+k2]   + r*A1[3*HID+k2];
        float v1v= q*A1[2*HID+k2+1] + r*A1[3*HID+k2+1];
        ushort2 uu, vv;
        uu.x = (unsigned short)f2s(u0); uu.y = (unsigned short)f2s(u1v);
        vv.x = (unsigned short)f2s(v0); vv.y = (unsigned short)f2s(v1v);
        *(ushort2*)((short*)u1 + (size_t)i*HID + k2) = uu;
        *(ushort2*)((short*)v1 + (size_t)i*HID + k2) = vv;
    } else if (blockIdx.x < 4672){
        __shared__ float sPx[256], sPy[256], sPz[256], sRho[256], sSr[256];
        __shared__ float sI[256];
        int bb = blockIdx.x - 4160;
        int mbase = (bb >> 3) * 256;
        {
            int i = mbase + tid;
            sPx[tid]=pos[3*i]; sPy[tid]=pos[3*i+1]; sPz[tid]=pos[3*i+2];
            float rad = feat[7*i+1], sc = feat[7*i+2];
            float rho = rad - OFFSETC;
            sRho[tid]=rho; sSr[tid]=sc*rho;
            sI[tid]=0.f;
        }
        __syncthreads();
        int T = bb*256 + tid;
        int s = T >> 3, p = T & 7;
        int sl = s & 255;
        int e0 = s*32 + p*4;
        float px = sPx[sl], py = sPy[sl], pz = sPz[sl];
        float sr = sSr[sl];
        const int* dP = ei + EGB;
        int4 d4 = *(const int4*)(dP + e0);
        int dls[4] = {d4.x&255, d4.y&255, d4.z&255, d4.w&255};
#pragma unroll
        for (int j=0;j<4;j++){
            int dl = dls[j];
            float dx = px - sPx[dl];
            float dy = py - sPy[dl];
            float dz = pz - sPz[dl];
            float d  = sqrtf(dx*dx+dy*dy+dz*dz + 1e-12f);
            float rho_i = sRho[dl];
            float U = d + sr;
            if (rho_i < U){
                float L = fmaxf(rho_i, fabsf(d - sr));
                float invU = 1.0f/U, invL = 1.0f/L;
                float I = 0.5f*invL - 0.5f*invU
                        + 0.125f*(d - sr*sr/d)*(invU*invU - invL*invL)
                        + 0.25f*__logf(L*invU)/d;
                atomicAdd(&sI[dl], I);
            }
        }
        __syncthreads();
        atomicAdd(&Isum[mbase + tid], sI[tid]);
    } else {
        int e = (blockIdx.x-4672)*256 + tid;
        int s = gei[e], dd = gei[EGNN+e];
        float dx = pos[3*s+0] - pos[3*dd+0];
        float dy = pos[3*s+1] - pos[3*dd+1];
        float dz = pos[3*s+2] - pos[3*dd+2];
        dgnn[e] = sqrtf(dx*dx+dy*dy+dz*dz + 1e-12f);
        atomicAdd(&cnt[dd], 1);
    }
}

// ============ MEGA-B: gbB per-atom + scan + CSR fill (LDS cursor) ============
__global__ __launch_bounds__(256) void k_B(
    const float* __restrict__ feat, const float* __restrict__ Isum,
    float* __restrict__ Bv, float* __restrict__ cB, float* __restrict__ gB,
    float* __restrict__ egb,
    const int* __restrict__ cnt, int* __restrict__ rptr,
    const int* __restrict__ gei, const float* __restrict__ dgnn,
    int* __restrict__ csr, int2* __restrict__ csr2)
{
    int t = threadIdx.x;
    if (blockIdx.x < 64){
        int i = blockIdx.x*256 + t;
        float q   = feat[7*i+0];
        float rad = feat[7*i+1];
        float rho = rad - OFFSETC;
        float psi = Isum[i]*rho;
        float u = psi*(ALPHAC + psi*(-BETAC + GAMMAC*psi));
        float tt = tanhf(u);
        float B = 1.0f/(1.0f/rho - tt/rad);
        Bv[i] = B;
        float du = ALPHAC + psi*(-2.0f*BETAC + 3.0f*GAMMAC*psi);
        cB[i] = B*B*((1.0f-tt*tt)/rad)*du*rho;
        float Cs = 0.5f*PREFC*q*q;
        egb[i] = Cs/B;
        gB[i]  = -Cs/(B*B);
    } else {
        __shared__ int sc[256];
        __shared__ int lcur[256];
        int m = blockIdx.x - 64;
        int c = cnt[m*256+t];
        sc[t] = c; __syncthreads();
        for (int off=1; off<256; off<<=1){
            int x = (t>=off) ? sc[t-off] : 0;
            __syncthreads();
            sc[t] += x;
            __syncthreads();
        }
        int exl = sc[t] - c;             // exclusive prefix, molecule-local
        rptr[m*256+t] = m*4096 + exl;
        lcur[t] = exl;
        __syncthreads();
        int e0 = m*4096;
        for (int j=t; j<4096; j+=256){
            int e = e0 + j;
            int dl = gei[EGNN+e] & 255;
            float d = dgnn[e];
            int p = atomicAdd(&lcur[dl], 1);
            int idx = e0 + p;
            csr[idx] = e;
            int2 rec; rec.x = (e >> 4) << 8;   // byte offset of src row (128 bf16)
            rec.y = __float_as_int(d);
            csr2[idx] = rec;
        }
    }
}

__global__ __launch_bounds__(256) void k_gbC(
    const float* __restrict__ pos, const float* __restrict__ feat,
    const int* __restrict__ ei, const float* __restrict__ Bv,
    float* __restrict__ egb, float* __restrict__ gdgb, float* __restrict__ gB)
{
    __shared__ float sPx[256], sPy[256], sPz[256], sB[256], sQf[256];
    __shared__ float sE[256], sG[256];
    int tid = threadIdx.x;
    int mbase = (blockIdx.x >> 3) * 256;
    {
        int i = mbase + tid;
        sPx[tid]=pos[3*i]; sPy[tid]=pos[3*i+1]; sPz[tid]=pos[3*i+2];
        sB[tid]=Bv[i]; sQf[tid]=feat[7*i+0];
        sE[tid]=0.f; sG[tid]=0.f;
    }
    __syncthreads();
    int T = blockIdx.x*256 + tid;
    int s = T >> 3, p = T & 7;
    int sl = s & 255;
    int e0 = s*32 + p*4;
    float px = sPx[sl], py = sPy[sl], pz = sPz[sl];
    float qs = sQf[sl];
    float Bs = sB[sl];
    float gsrc = 0.f;
    const int* dP = ei + EGB;
    int4 d4 = *(const int4*)(dP + e0);
    int dls[4] = {d4.x&255, d4.y&255, d4.z&255, d4.w&255};
#pragma unroll
    for (int j=0;j<4;j++){
        int dl = dls[j];
        float dx = px - sPx[dl];
        float dy = py - sPy[dl];
        float dz = pz - sPz[dl];
        float d2 = dx*dx+dy*dy+dz*dz + 1e-12f;
        float d  = sqrtf(d2);
        float Bd = sB[dl];
        float C = 0.5f*PREFC*sQf[dl]*qs;
        float P = Bd*Bs;
        float ex = __expf(-d2/(4.f*P));
        float f2 = d2 + P*ex;
        float f  = sqrtf(f2);
        float f3i = 1.f/(f2*f);
        gdgb[e0+j] = -C*d*(1.f - 0.25f*ex)*f3i;
        float common = -C*ex*(1.f + d2/(4.f*P))*0.5f*f3i;
        atomicAdd(&sE[dl], C/f);
        atomicAdd(&sG[dl], common*Bs);
        gsrc += common*Bd;
    }
    gsrc += __shfl_xor(gsrc,1);
    gsrc += __shfl_xor(gsrc,2);
    gsrc += __shfl_xor(gsrc,4);
    if (p==0) atomicAdd(&sG[sl], gsrc);
    __syncthreads();
    atomicAdd(&egb[mbase + tid], sE[tid]);
    atomicAdd(&gB[mbase + tid],  sG[tid]);
}

__global__ __launch_bounds__(256) void k_gbE(
    const float* __restrict__ pos, const float* __restrict__ feat,
    const int* __restrict__ ei, const float* __restrict__ cB,
    const float* __restrict__ gB,
    const float* __restrict__ gdgb, float* __restrict__ grad)
{
    __shared__ float sPx[256], sPy[256], sPz[256], sRho[256], sSr[256], sCg[256];
    __shared__ float sGx[256], sGy[256], sGz[256];
    int tid = threadIdx.x;
    int mbase = (blockIdx.x >> 3) * 256;
    {
        int i = mbase + tid;
        sPx[tid]=pos[3*i]; sPy[tid]=pos[3*i+1]; sPz[tid]=pos[3*i+2];
        float rad = feat[7*i+1], sc = feat[7*i+2];
        float rho = rad - OFFSETC;
        sRho[tid]=rho; sSr[tid]=sc*rho;
        sCg[tid]=cB[i]*gB[i];
        sGx[tid]=0.f; sGy[tid]=0.f; sGz[tid]=0.f;
    }
    __syncthreads();
    int T = blockIdx.x*256 + tid;
    int s = T >> 3, p = T & 7;
    int sl = s & 255;
    int e0 = s*32 + p*4;
    float px = sPx[sl], py = sPy[sl], pz = sPz[sl];
    float sr = sSr[sl];
    float gx=0.f, gy=0.f, gz=0.f;
    const int* dP = ei + EGB;
    int4 d4 = *(const int4*)(dP + e0);
    int dls[4] = {d4.x&255, d4.y&255, d4.z&255, d4.w&255};
#pragma unroll
    for (int j=0;j<4;j++){
        int dl = dls[j];
        float dx = px - sPx[dl];
        float dy = py - sPy[dl];
        float dz = pz - sPz[dl];
        float d2 = dx*dx+dy*dy+dz*dz + 1e-12f;
        float d  = sqrtf(d2);
        float rho_i = sRho[dl];
        float U = d + sr;
        float gd = gdgb[e0+j];
        if (rho_i < U){
            float aa = fabsf(d - sr);
            float L, Lp;
            if (rho_i >= aa){ L = rho_i; Lp = 0.f; }
            else { L = aa; Lp = (d >= sr) ? 1.f : -1.f; }
            float invU = 1.f/U, invL = 1.f/L;
            float invU2=invU*invU, invL2=invL*invL;
            float dIdd = -0.5f*Lp*invL2 + 0.5f*invU2
                + 0.125f*(1.f + sr*sr/d2)*(invU2 - invL2)
                + 0.125f*(d - sr*sr/d)*(2.f*Lp*invL2*invL - 2.f*invU2*invU)
                + 0.25f*((Lp*invL - invU)/d - __logf(L*invU)/d2);
            gd += sCg[dl]*dIdd;
        }
        float c = gd/d;
        gx += c*dx; gy += c*dy; gz += c*dz;
        atomicAdd(&sGx[dl], -c*dx);
        atomicAdd(&sGy[dl], -c*dy);
        atomicAdd(&sGz[dl], -c*dz);
    }
    gx += __shfl_xor(gx,1); gx += __shfl_xor(gx,2); gx += __shfl_xor(gx,4);
    gy += __shfl_xor(gy,1); gy += __shfl_xor(gy,2); gy += __shfl_xor(gy,4);
    gz += __shfl_xor(gz,1); gz += __shfl_xor(gz,2); gz += __shfl_xor(gz,4);
    if (p==0){
        atomicAdd(&sGx[sl], gx);
        atomicAdd(&sGy[sl], gy);
        atomicAdd(&sGz[sl], gz);
    }
    __syncthreads();
    int i = mbase + tid;
    atomicAdd(&grad[3*i+0], sGx[tid]);
    atomicAdd(&grad[3*i+1], sGy[tid]);
    atomicAdd(&grad[3*i+2], sGz[tid]);
}

// ============ wave-per-node edge passes (no LDS, no barriers, 2 k per lane) ====

// forward dst aggregation: Hs[dst][k] = sum silu(a); optional Sds = sum silu'(a)
__device__ __forceinline__ void edge_fwd_wave(
    int dst, int lane,
    const int2* __restrict__ csr2, const int* __restrict__ rptr, const int* __restrict__ cnt,
    const uint* __restrict__ u, const uint* __restrict__ v,
    const float* __restrict__ wdp, const float* __restrict__ bb,
    uint* __restrict__ Hs, uint* __restrict__ Sds)
{
    int n = cnt[dst], r0 = rptr[dst];
    float2 wd = *(const float2*)&wdp[2*lane];
    float2 b2 = *(const float2*)&bb[2*lane];
    uint vp = v[dst*64 + lane];
    float base0 = lo2f(vp) + b2.x;
    float base1 = hi2f(vp) + b2.y;
    float h0=0.f,h1=0.f,e0a=0.f,e1a=0.f;
    for (int j0=0; j0<n; j0+=64){
        int m = n - j0; if (m > 64) m = 64;
        int rx = 0, ry = 0;
        if (lane < m){ int2 rc = csr2[r0+j0+lane]; rx = rc.x; ry = rc.y; }
#pragma unroll 2
        for (int j=0;j<m;j++){
            int off = __builtin_amdgcn_readlane(rx, j);
            float d  = __uint_as_float((unsigned)__builtin_amdgcn_readlane(ry, j));
            uint up = *(const uint*)((const char*)u + off + 4*lane);
            float a0 = fmaf(d, wd.x, base0 + lo2f(up));
            float a1 = fmaf(d, wd.y, base1 + hi2f(up));
            float s0 = sigf(a0), s1 = sigf(a1);
            float p0 = a0*s0, p1 = a1*s1;
            h0 += p0; h1 += p1;
            e0a = fmaf(s0, 1.f + a0 - p0, e0a);
            e1a = fmaf(s1, 1.f + a1 - p1, e1a);
        }
    }
    Hs[dst*64+lane] = pack2(h0,h1);
    if (Sds) Sds[dst*64+lane] = pack2(e0a,e1a);
}

__global__ __launch_bounds__(256,8) void k_edge_fwd(
    const int2* __restrict__ csr2, const int* __restrict__ rptr, const int* __restrict__ cnt,
    const uint* __restrict__ u, const uint* __restrict__ v,
    const float* __restrict__ wdp, const float* __restrict__ bb,
    uint* __restrict__ Hs, uint* __restrict__ Sds)
{
    int lane = threadIdx.x & 63, wid = threadIdx.x >> 6;
    int dst = blockIdx.x*4 + wid;
    edge_fwd_wave(dst, lane, csr2, rptr, cnt, u, v, wdp, bb, Hs, Sds);
}

// l3: dst role computes Gd + x3; src role computes Gs + gdg  (fused launch)
__global__ __launch_bounds__(256,8) void k_l3(
    const int2* __restrict__ csr2, const int* __restrict__ rptr, const int* __restrict__ cnt,
    const int* __restrict__ gei, const float* __restrict__ dgnn,
    const uint* __restrict__ u, const uint* __restrict__ v,
    const float* __restrict__ A3, const float* __restrict__ B3,
    const float* __restrict__ C3, const float* __restrict__ D3,
    uint* __restrict__ Gd, float* __restrict__ x3,
    uint* __restrict__ Gs, float* __restrict__ gdg)
{
    int lane = threadIdx.x & 63, wid = threadIdx.x >> 6;
    const float* wdp = A3 + 256*HID;
    if (blockIdx.x < NATOMS/4){
        int dst = blockIdx.x*4 + wid;
        int n = cnt[dst], r0 = rptr[dst];
        float2 wd = *(const float2*)&wdp[2*lane];
        float2 b2 = *(const float2*)&B3[2*lane];
        float2 ck = *(const float2*)&C3[2*lane];
        uint vp = v[dst*64 + lane];
        float base0 = lo2f(vp) + b2.x;
        float base1 = hi2f(vp) + b2.y;
        float h0=0.f,h1=0.f,e0a=0.f,e1a=0.f;
        for (int j0=0; j0<n; j0+=64){
            int m = n - j0; if (m > 64) m = 64;
            int rx = 0, ry = 0;
            if (lane < m){ int2 rc = csr2[r0+j0+lane]; rx = rc.x; ry = rc.y; }
#pragma unroll 2
            for (int j=0;j<m;j++){
                int off = __builtin_amdgcn_readlane(rx, j);
                float d  = __uint_as_float((unsigned)__builtin_amdgcn_readlane(ry, j));
                uint up = *(const uint*)((const char*)u + off + 4*lane);
                float a0 = fmaf(d, wd.x, base0 + lo2f(up));
                float a1 = fmaf(d, wd.y, base1 + hi2f(up));
                float s0 = sigf(a0), s1 = sigf(a1);
                float p0 = a0*s0, p1 = a1*s1;
                h0 += p0; h1 += p1;
                e0a = fmaf(s0, 1.f + a0 - p0, e0a);
                e1a = fmaf(s1, 1.f + a1 - p1, e1a);
            }
        }
        Gd[dst*64+lane] = pack2(ck.x*e0a, ck.y*e1a);
        float px = waveRed(ck.x*h0 + ck.y*h1);
        if (lane==0) x3[dst] = px + (float)n*D3[0];
    } else {
        int s = (blockIdx.x - NATOMS/4)*4 + wid;
        int doff = 0, dbit = 0;
        if (lane < 16){
            doff = gei[EGNN + s*16 + lane] << 8;
            dbit = __float_as_int(dgnn[s*16+lane]);
        }
        float2 wd = *(const float2*)&wdp[2*lane];
        float2 b2 = *(const float2*)&B3[2*lane];
        float2 ck = *(const float2*)&C3[2*lane];
        uint up = u[s*64 + lane];
        float us0 = lo2f(up) + b2.x;
        float us1 = hi2f(up) + b2.y;
        float cw0 = ck.x*wd.x, cw1 = ck.y*wd.y;
        float gs0=0.f, gs1=0.f, acc=0.f;
#pragma unroll
        for (int t=0;t<16;t++){
            int off = __builtin_amdgcn_readlane(doff, t);
            float d = __uint_as_float((unsigned)__builtin_amdgcn_readlane(dbit, t));
            uint vp = *(const uint*)((const char*)v + off + 4*lane);
            float a0 = fmaf(d, wd.x, us0 + lo2f(vp));
            float a1 = fmaf(d, wd.y, us1 + hi2f(vp));
            float s0 = sigf(a0), s1 = sigf(a1);
            float p0 = a0*s0, p1 = a1*s1;
            float dv0 = s0*(1.f + a0 - p0);
            float dv1 = s1*(1.f + a1 - p1);
            gs0 += dv0; gs1 += dv1;
            float pg = fmaf(dv1, cw1, dv0*cw0);
            pg = waveRed(pg);
            acc = (lane==t) ? pg : acc;
        }
        Gs[s*64+lane] = pack2(ck.x*gs0, ck.y*gs1);
        if (lane < 16) gdg[s*16+lane] = acc;
    }
}

// backward src pass for layer 2 / layer 1: recompute dv, multiply by gH[dst]
__global__ __launch_bounds__(256,8) void k_bwd_src(
    const int* __restrict__ gei, const float* __restrict__ dgnn,
    const uint* __restrict__ u, const uint* __restrict__ v,
    const float* __restrict__ wdp, const float* __restrict__ bb,
    const uint* __restrict__ gH,
    uint* __restrict__ Gs, float* __restrict__ gdg)
{
    int lane = threadIdx.x & 63, wid = threadIdx.x >> 6;
    int s = blockIdx.x*4 + wid;
    int doff = 0, dbit = 0; float gold = 0.f;
    if (lane < 16){
        doff = gei[EGNN + s*16 + lane] << 8;
        dbit = __float_as_int(dgnn[s*16+lane]);
        gold = gdg[s*16+lane];
    }
    float2 wd = *(const float2*)&wdp[2*lane];
    float2 b2 = *(const float2*)&bb[2*lane];
    uint up = u[s*64 + lane];
    float us0 = lo2f(up) + b2.x;
    float us1 = hi2f(up) + b2.y;
    float gs0=0.f, gs1=0.f, acc=0.f;
#pragma unroll
    for (int t=0;t<16;t++){
        int off = __builtin_amdgcn_readlane(doff, t);
        float d = __uint_as_float((unsigned)__builtin_amdgcn_readlane(dbit, t));
        uint vp = *(const uint*)((const char*)v + off + 4*lane);
        uint gp = *(const uint*)((const char*)gH + off + 4*lane);
        float a0 = fmaf(d, wd.x, us0 + lo2f(vp));
        float a1 = fmaf(d, wd.y, us1 + hi2f(vp));
        float s0 = sigf(a0), s1 = sigf(a1);
        float p0 = a0*s0, p1 = a1*s1;
        float ga0 = s0*(1.f + a0 - p0) * lo2f(gp);
        float ga1 = s1*(1.f + a1 - p1) * hi2f(gp);
        gs0 += ga0; gs1 += ga1;
        float pg = fmaf(ga1, wd.y, ga0*wd.x);
        pg = waveRed(pg);
        acc = (lane==t) ? pg : acc;
    }
    if (Gs) Gs[s*64+lane] = pack2(gs0, gs1);
    if (lane < 16) gdg[s*16+lane] = gold + acc;
}

// MFMA node forward
__global__ __launch_bounds__(256) void k_node_fwd_uv_mfma(
    const short* __restrict__ Hs, const int* __restrict__ cnt,
    const short* __restrict__ Ct, const float* __restrict__ D,
    const short* __restrict__ Aat, const short* __restrict__ Abt,
    bf* __restrict__ dsz, bf* __restrict__ u, bf* __restrict__ v)
{
    __shared__ short sx[64*HID];
    int lane = threadIdx.x & 63, w = threadIdx.x >> 6;
    int m0 = blockIdx.x*64 + w*16;
    int ar = lane & 15, kg = lane >> 4;
    bf8v af[4];
#pragma unroll
    for (int s=0;s<4;s++) af[s] = *(const bf8v*)&Hs[(size_t)(m0+ar)*HID + s*32 + kg*8];
    f4v acc[8];
#pragma unroll
    for (int nt=0;nt<8;nt++){
        acc[nt] = (f4v){0.f,0.f,0.f,0.f};
        const short* bp = Ct + (nt*16+ar)*HID + kg*8;
#pragma unroll
        for (int s=0;s<4;s++){
            bf8v bv = *(const bf8v*)(bp + s*32);
            acc[nt] = __builtin_amdgcn_mfma_f32_16x16x32_bf16(af[s], bv, acc[nt], 0,0,0);
        }
    }
    float cn[4];
#pragma unroll
    for (int r=0;r<4;r++) cn[r] = (float)cnt[m0 + kg*4 + r];
#pragma unroll
    for (int nt=0;nt<8;nt++){
        int j = nt*16 + ar;
        float Dj = D[j];
#pragma unroll
        for (int r=0;r<4;r++){
            int m = m0 + kg*4 + r;
            float zv = acc[nt][r] + cn[r]*Dj;
            float sg = sigf(zv);
            dsz[(size_t)m*HID + j] = f2b(sg*(1.f + zv*(1.f - sg)));
            sx[(w*16 + kg*4 + r)*HID + j] = f2s(zv*sg);
        }
    }
    __syncthreads();
#pragma unroll
    for (int s=0;s<4;s++) af[s] = *(const bf8v*)&sx[(w*16+ar)*HID + s*32 + kg*8];
    f4v au[8], av[8];
#pragma unroll
    for (int nt=0;nt<8;nt++){
        au[nt] = (f4v){0.f,0.f,0.f,0.f};
        av[nt] = (f4v){0.f,0.f,0.f,0.f};
        const short* bpa = Aat + (nt*16+ar)*HID + kg*8;
        const short* bpb = Abt + (nt*16+ar)*HID + kg*8;
#pragma unroll
        for (int s=0;s<4;s++){
            bf8v ba = *(const bf8v*)(bpa + s*32);
            bf8v bb = *(const bf8v*)(bpb + s*32);
            au[nt] = __builtin_amdgcn_mfma_f32_16x16x32_bf16(af[s], ba, au[nt], 0,0,0);
            av[nt] = __builtin_amdgcn_mfma_f32_16x16x32_bf16(af[s], bb, av[nt], 0,0,0);
        }
    }
#pragma unroll
    for (int nt=0;nt<8;nt++){
        int j = nt*16 + ar;
#pragma unroll
        for (int r=0;r<4;r++){
            int m = m0 + kg*4 + r;
            u[(size_t)m*HID + j] = f2b(au[nt][r]);
            v[(size_t)m*HID + j] = f2b(av[nt][r]);
        }
    }
}

// MFMA node backward. If Sds != nullptr: Gd frag = gHin ⊙ Sds.
__global__ __launch_bounds__(256) void k_gx_node_bwd_mfma(
    const short* __restrict__ Gs, const short* __restrict__ Gd,
    const short* __restrict__ gHin, const short* __restrict__ Sds,
    const short* __restrict__ Ra, const short* __restrict__ Rb,
    const bf* __restrict__ dsz, const short* __restrict__ Rc,
    bf* __restrict__ gHout)
{
    __shared__ short st[64*HID];
    int lane = threadIdx.x & 63, w = threadIdx.x >> 6;
    int m0 = blockIdx.x*64 + w*16;
    int ar = lane & 15, kg = lane >> 4;
    bf8v as_[4], ad_[4];
#pragma unroll
    for (int s=0;s<4;s++)
        as_[s] = *(const bf8v*)&Gs[(size_t)(m0+ar)*HID + s*32 + kg*8];
    if (Sds){
#pragma unroll
        for (int s=0;s<4;s++){
            bf8v g = *(const bf8v*)&gHin[(size_t)(m0+ar)*HID + s*32 + kg*8];
            bf8v sd = *(const bf8v*)&Sds[(size_t)(m0+ar)*HID + s*32 + kg*8];
            bf8v r;
#pragma unroll
            for (int i=0;i<8;i++) r[i] = f2s(s2f(g[i])*s2f(sd[i]));
            ad_[s] = r;
        }
    } else {
#pragma unroll
        for (int s=0;s<4;s++)
            ad_[s] = *(const bf8v*)&Gd[(size_t)(m0+ar)*HID + s*32 + kg*8];
    }
    f4v acc[8];
#pragma unroll
    for (int nt=0;nt<8;nt++){
        acc[nt] = (f4v){0.f,0.f,0.f,0.f};
        const short* bpa = Ra + (nt*16+ar)*HID + kg*8;
        const short* bpb = Rb + (nt*16+ar)*HID + kg*8;
#pragma unroll
        for (int s=0;s<4;s++){
            bf8v ba = *(const bf8v*)(bpa + s*32);
            bf8v bb = *(const bf8v*)(bpb + s*32);
            acc[nt] = __builtin_amdgcn_mfma_f32_16x16x32_bf16(as_[s], ba, acc[nt], 0,0,0);
            acc[nt] = __builtin_amdgcn_mfma_f32_16x16x32_bf16(ad_[s], bb, acc[nt], 0,0,0);
        }
    }
#pragma unroll
    for (int nt=0;nt<8;nt++){
        int j = nt*16 + ar;
#pragma unroll
        for (int r=0;r<4;r++){
            int m = m0 + kg*4 + r;
            float t = acc[nt][r] * b2f(dsz[(size_t)m*HID + j]);
            st[(w*16 + kg*4 + r)*HID + j] = f2s(t);
        }
    }
    __syncthreads();
    bf8v af[4];
#pragma unroll
    for (int s=0;s<4;s++) af[s] = *(const bf8v*)&st[(w*16+ar)*HID + s*32 + kg*8];
    f4v a2[8];
#pragma unroll
    for (int nt=0;nt<8;nt++){
        a2[nt] = (f4v){0.f,0.f,0.f,0.f};
        const short* bp = Rc + (nt*16+ar)*HID + kg*8;
#pragma unroll
        for (int s=0;s<4;s++){
            bf8v bc = *(const bf8v*)(bp + s*32);
            a2[nt] = __builtin_amdgcn_mfma_f32_16x16x32_bf16(af[s], bc, a2[nt], 0,0,0);
        }
    }
#pragma unroll
    for (int nt=0;nt<8;nt++){
        int j = nt*16 + ar;
#pragma unroll
        for (int r=0;r<4;r++){
            gHout[(size_t)(m0 + kg*4 + r)*HID + j] = f2b(a2[nt][r]);
        }
    }
}

// ============ fused outputs: forces + per-molecule energies ============
__global__ __launch_bounds__(256) void k_out(
    const float* __restrict__ pos, const int* __restrict__ gei,
    const int* __restrict__ csr, const int* __restrict__ rptr, const int* __restrict__ cnt,
    const float* __restrict__ dgnn, const float* __restrict__ gdg,
    const float* __restrict__ grad,
    const float* __restrict__ egb, const float* __restrict__ x3,
    float* __restrict__ out)
{
    int tid = threadIdx.x;
    if (blockIdx.x < 512){
        float* fout = out + MOLS;
        int T = blockIdx.x*256 + tid;
        int i = T >> 3, p = T & 7;
        float px = pos[3*i+0], py = pos[3*i+1], pz = pos[3*i+2];
        float ax=0.f, ay=0.f, az=0.f;
        for (int j=p;j<16;j+=8){
            int e = i*16 + j;
            int o = gei[EGNN+e];
            float c = gdg[e]/dgnn[e];
            ax += c*(px - pos[3*o+0]);
            ay += c*(py - pos[3*o+1]);
            az += c*(pz - pos[3*o+2]);
        }
        int n = cnt[i], r0 = rptr[i];
        for (int j=p;j<n;j+=8){
            int e = csr[r0+j];
            int o = e >> 4;
            float c = gdg[e]/dgnn[e];
            ax += c*(px - pos[3*o+0]);
            ay += c*(py - pos[3*o+1]);
            az += c*(pz - pos[3*o+2]);
        }
        ax += __shfl_xor(ax,1); ax += __shfl_xor(ax,2); ax += __shfl_xor(ax,4);
        ay += __shfl_xor(ay,1); ay += __shfl_xor(ay,2); ay += __shfl_xor(ay,4);
        az += __shfl_xor(az,1); az += __shfl_xor(az,2); az += __shfl_xor(az,4);
        if (p==0){
            fout[3*i+0] = -(grad[3*i+0] + ax);
            fout[3*i+1] = -(grad[3*i+1] + ay);
            fout[3*i+2] = -(grad[3*i+2] + az);
        }
    } else {
        __shared__ float red[4];
        int m = blockIdx.x - 512;
        int i = m*ATOMSM + tid;
        float en = egb[i] + x3[i];
        float v = waveRed(en);
        int wave = tid>>6, lane = tid&63;
        if (lane==0) red[wave] = v;
        __syncthreads();
        if (tid==0) out[m] = red[0]+red[1]+red[2]+red[3];
    }
}

extern "C" void kernel_launch(void* const* d_in, const int* in_sizes, int n_in,
                              void* d_out, int out_size, void* d_ws, size_t ws_size,
                              hipStream_t stream)
{
    const float* pos  = (const float*)d_in[0];
    const float* feat = (const float*)d_in[1];
    const int* ei  = (const int*)d_in[3];
    const int* gei = (const int*)d_in[4];
    const float* A1f = (const float*)d_in[5];  const float* B1f = (const float*)d_in[6];
    const float* C1f = (const float*)d_in[7];  const float* D1f = (const float*)d_in[8];
    const float* A2f = (const float*)d_in[9];  const float* B2f = (const float*)d_in[10];
    const float* C2f = (const float*)d_in[11]; const float* D2f = (const float*)d_in[12];
    const float* A3f = (const float*)d_in[13]; const float* B3f = (const float*)d_in[14];
    const float* C3f = (const float*)d_in[15]; const float* D3f = (const float*)d_in[16];

    float* w = (float*)d_ws;
    size_t off = 0;
    auto nxt = [&](size_t n)->float*{ float* p = w + off; off += (n + 255) & ~(size_t)255; return p; };
    // contiguous zero-init region: Isum | cnt | grad  (5*NATOMS floats)
    float* Isum = nxt(NATOMS);
    int*   cnt  = (int*)nxt(NATOMS);
    float* grad = nxt(3*NATOMS);
    float* Bv = nxt(NATOMS); float* cB = nxt(NATOMS);
    float* gB = nxt(NATOMS); float* egb = nxt(NATOMS); float* x3 = nxt(NATOMS);
    int*   rptr = (int*)nxt(NATOMS);
    int*   csr  = (int*)nxt(EGNN);
    int2*  csr2 = (int2*)nxt((size_t)EGNN*2);
    float* dgnn = nxt(EGNN); float* gdgnn = nxt(EGNN); float* gdgb = nxt(EGB);
    bf* dsz1 = (bf*)nxt(NH/2); bf* dsz2 = (bf*)nxt(NH/2);
    bf* Hs1 = (bf*)nxt(NH/2); bf* Hs2 = (bf*)nxt(NH/2);
    bf* Gs3 = (bf*)nxt(NH/2); bf* Gd3 = (bf*)nxt(NH/2);
    bf* Sds2 = (bf*)nxt(NH/2);
    bf* u1 = (bf*)nxt(NH/2); bf* v1 = (bf*)nxt(NH/2);
    bf* u2 = (bf*)nxt(NH/2); bf* v2 = (bf*)nxt(NH/2);
    bf* v3 = (bf*)nxt(NH/2);
    short* C1t  = (short*)nxt(8192); short* C2t  = (short*)nxt(8192);
    short* A2at = (short*)nxt(8192); short* A2bt = (short*)nxt(8192);
    short* A3at = (short*)nxt(8192); short* A3bt = (short*)nxt(8192);
    short* rA2a = (short*)nxt(8192); short* rA2b = (short*)nxt(8192);
    short* rA3a = (short*)nxt(8192); short* rA3b = (short*)nxt(8192);
    short* rC1  = (short*)nxt(8192); short* rC2  = (short*)nxt(8192);
    // aliases:
    bf* u3  = Hs1;      // Hs1 dead after node_fwd #1
    bf* gH2 = Hs2;      // Hs2 dead after node_fwd #2
    bf* Gs2 = Gs3;      // dead after gx_node_bwd(3->2)
    bf* gH1 = u3;       // u3 dead after l3 kernel

    // single combined zero-init (Isum|cnt|grad are contiguous)
    hipMemsetAsync(Isum, 0, (size_t)5*NATOMS*sizeof(float), stream);

    // MEGA-A: weights + uv1 + gbA + dist
    k_A<<<64 + NH/512 + 512 + EGNN/256, 256, 0, stream>>>(
        A2f, C1f, A3f, C2f,
        C1t, C2t, A2at, A2bt, A3at, A3bt, rA2a, rA2b, rA3a, rA3b, rC1, rC2,
        feat, A1f, u1, v1,
        pos, ei, Isum, gei, dgnn, cnt);

    // MEGA-B: gbB + scan + fill (LDS cursors)
    k_B<<<128,256,0,stream>>>(feat, Isum, Bv, cB, gB, egb, cnt, rptr,
                              gei, dgnn, csr, csr2);

    // forward layer 1 (wave-per-dst)
    k_edge_fwd<<<NATOMS/4,256,0,stream>>>(csr2, rptr, cnt, (const uint*)u1, (const uint*)v1,
                                          A1f+4*HID, B1f, (uint*)Hs1, (uint*)nullptr);
    k_gbC<<<512,256,0,stream>>>(pos, feat, ei, Bv, egb, gdgb, gB);
    k_node_fwd_uv_mfma<<<NATOMS/64,256,0,stream>>>((const short*)Hs1, cnt, C1t, D1f,
                                                   A2at, A2bt, dsz1, u2, v2);
    // forward layer 2
    k_edge_fwd<<<NATOMS/4,256,0,stream>>>(csr2, rptr, cnt, (const uint*)u2, (const uint*)v2,
                                          A2f+256*HID, B2f, (uint*)Hs2, (uint*)Sds2);
    k_gbE<<<512,256,0,stream>>>(pos, feat, ei, cB, gB, gdgb, grad);
    k_node_fwd_uv_mfma<<<NATOMS/64,256,0,stream>>>((const short*)Hs2, cnt, C2t, D2f,
                                                   A3at, A3bt, dsz2, u3, v3);

    // layer-3 fused dst+src (wave-per-node)
    k_l3<<<2*(NATOMS/4),256,0,stream>>>(csr2, rptr, cnt, gei, dgnn,
                                        (const uint*)u3, (const uint*)v3,
                                        A3f, B3f, C3f, D3f,
                                        (uint*)Gd3, x3, (uint*)Gs3, gdgnn);

    // backward chain
    k_gx_node_bwd_mfma<<<NATOMS/64,256,0,stream>>>((const short*)Gs3, (const short*)Gd3,
        (const short*)nullptr, (const short*)nullptr, rA3a, rA3b, dsz2, rC2, gH2);
    k_bwd_src<<<NATOMS/4,256,0,stream>>>(gei, dgnn, (const uint*)u2, (const uint*)v2,
                                         A2f+256*HID, B2f, (const uint*)gH2,
                                         (uint*)Gs2, gdgnn);
    k_gx_node_bwd_mfma<<<NATOMS/64,256,0,stream>>>((const short*)Gs2, (const short*)nullptr,
        (const short*)gH2, (const short*)Sds2, rA2a, rA2b, dsz1, rC1, gH1);
    k_bwd_src<<<NATOMS/4,256,0,stream>>>(gei, dgnn, (const uint*)u1, (const uint*)v1,
                                         A1f+4*HID, B1f, (const uint*)gH1,
                                         (uint*)nullptr, gdgnn);

    // fused outputs (forces + energies)
    k_out<<<576,256,0,stream>>>(pos, gei, csr, rptr, cnt, dgnn, gdgnn,
                                grad, egb, x3, (float*)d_out);
}

// Round 4
// 328.900 us; speedup vs baseline: 1.2479x; 1.2479x over previous
//
#include <hip/hip_runtime.h>
#include <hip/hip_bf16.h>

#define NATOMS 16384
#define MOLS   64
#define ATOMSM 256
#define EGB    524288
#define EGNN   262144
#define HID    128
#define NH     (NATOMS*HID)

#define OFFSETC 0.009f
#define ALPHAC  1.0f
#define BETAC   0.8f
#define GAMMAC  4.85f
#define PREFC   (-138.935456f*(1.0f-1.0f/78.5f))

typedef __hip_bfloat16 bf;
typedef __attribute__((ext_vector_type(8))) short bf8v;
typedef __attribute__((ext_vector_type(4))) float f4v;
typedef unsigned int uint;

__device__ __forceinline__ float b2f(bf x){ return __bfloat162float(x); }
__device__ __forceinline__ bf f2b(float x){ return __float2bfloat16(x); }
__device__ __forceinline__ short f2s(float x){ bf h = f2b(x); return *(short*)&h; }
__device__ __forceinline__ float s2f(short s){
    unsigned int x = ((unsigned int)(unsigned short)s) << 16;
    return __uint_as_float(x);
}
__device__ __forceinline__ float frcp(float x){ return __builtin_amdgcn_rcpf(x); }
__device__ __forceinline__ float frsq(float x){ return __builtin_amdgcn_rsqf(x); }
__device__ __forceinline__ float fsqrt(float x){ return __builtin_amdgcn_sqrtf(x); }
// fast sigmoid: v_mul+v_exp+v_add+v_rcp (avoids IEEE div sequence; -O3 has no fast-math)
__device__ __forceinline__ float sigf(float x){ return frcp(1.0f+__expf(-x)); }
__device__ __forceinline__ float waveRed(float v){
    v += __shfl_xor(v,32); v += __shfl_xor(v,16); v += __shfl_xor(v,8);
    v += __shfl_xor(v,4);  v += __shfl_xor(v,2);  v += __shfl_xor(v,1);
    return v;
}
__device__ __forceinline__ uint pack2(float a, float b){
    return (uint)(unsigned short)f2s(a) | ((uint)(unsigned short)f2s(b) << 16);
}
__device__ __forceinline__ float lo2f(uint w){ return __uint_as_float(w << 16); }
__device__ __forceinline__ float hi2f(uint w){ return __uint_as_float(w & 0xffff0000u); }

// butterfly reduction of 16 independent sums across 64 lanes.
// post: lane l holds total of A[(l>>1)&15] (17 shuffles vs 96 for per-edge waveRed).
__device__ __forceinline__ float red16(float (&A)[16], int lane){
#pragma unroll
    for (int i=0;i<8;i++){
        float send = (lane & 16) ? A[i] : A[i+8];
        float recv = __shfl_xor(send, 16);
        A[i] = ((lane & 16) ? A[i+8] : A[i]) + recv;
    }
#pragma unroll
    for (int i=0;i<4;i++){
        float send = (lane & 8) ? A[i] : A[i+4];
        float recv = __shfl_xor(send, 8);
        A[i] = ((lane & 8) ? A[i+4] : A[i]) + recv;
    }
#pragma unroll
    for (int i=0;i<2;i++){
        float send = (lane & 4) ? A[i] : A[i+2];
        float recv = __shfl_xor(send, 4);
        A[i] = ((lane & 4) ? A[i+2] : A[i]) + recv;
    }
    {
        float send = (lane & 2) ? A[0] : A[1];
        float recv = __shfl_xor(send, 2);
        A[0] = ((lane & 2) ? A[1] : A[0]) + recv;
    }
    A[0] += __shfl_xor(A[0], 32);
    A[0] += __shfl_xor(A[0], 1);
    return A[0];
}

// ============ MEGA-A: weight prep + uv1 + gbA + gnn-dist ============
__global__ __launch_bounds__(256) void k_A(
    const float* __restrict__ A2, const float* __restrict__ C1,
    const float* __restrict__ A3, const float* __restrict__ C2,
    short* __restrict__ C1t, short* __restrict__ C2t,
    short* __restrict__ A2at, short* __restrict__ A2bt,
    short* __restrict__ A3at, short* __restrict__ A3bt,
    short* __restrict__ rA2a, short* __restrict__ rA2b,
    short* __restrict__ rA3a, short* __restrict__ rA3b,
    short* __restrict__ rC1, short* __restrict__ rC2,
    const float* __restrict__ feat, const float* __restrict__ A1,
    bf* __restrict__ u1, bf* __restrict__ v1,
    const float* __restrict__ pos, const int* __restrict__ ei,
    float* __restrict__ Isum,
    const int* __restrict__ gei, float* __restrict__ dgnn, int* __restrict__ cnt)
{
    int tid = threadIdx.x;
    if (blockIdx.x < 64){
        int gid = blockIdx.x*256 + tid;
        int j = gid >> 7, k = gid & 127;
        C1t[gid]  = f2s(C1[k*HID+j]);
        C2t[gid]  = f2s(C2[k*HID+j]);
        A2at[gid] = f2s(A2[k*HID+j]);
        A2bt[gid] = f2s(A2[(HID+k)*HID+j]);
        A3at[gid] = f2s(A3[k*HID+j]);
        A3bt[gid] = f2s(A3[(HID+k)*HID+j]);
        rA2a[gid] = f2s(A2[gid]);
        rA2b[gid] = f2s(A2[HID*HID+gid]);
        rA3a[gid] = f2s(A3[gid]);
        rA3b[gid] = f2s(A3[HID*HID+gid]);
        rC1[gid]  = f2s(C1[gid]);
        rC2[gid]  = f2s(C2[gid]);
    } else if (blockIdx.x < 4160){
        int gid2 = (blockIdx.x-64)*256 + tid;   // [0, NH/2)
        int i = gid2 >> 6, k2 = (gid2 & 63)*2;
        float q = feat[7*i+0], r = feat[7*i+1];
        float u0 = q*A1[k2]         + r*A1[HID+k2];
        float u1v= q*A1[k2+1]       + r*A1[HID+k2+1];
        float v0 = q*A1[2*HID+k2]   + r*A1[3*HID+k2];
        float v1v= q*A1[2*HID+k2+1] + r*A1[3*HID+k2+1];
        ushort2 uu, vv;
        uu.x = (unsigned short)f2s(u0); uu.y = (unsigned short)f2s(u1v);
        vv.x = (unsigned short)f2s(v0); vv.y = (unsigned short)f2s(v1v);
        *(ushort2*)((short*)u1 + (size_t)i*HID + k2) = uu;
        *(ushort2*)((short*)v1 + (size_t)i*HID + k2) = vv;
    } else if (blockIdx.x < 4672){
        __shared__ float sPx[256], sPy[256], sPz[256], sRho[256], sSr[256];
        __shared__ float sI[256];
        int bb = blockIdx.x - 4160;
        int mbase = (bb >> 3) * 256;
        {
            int i = mbase + tid;
            sPx[tid]=pos[3*i]; sPy[tid]=pos[3*i+1]; sPz[tid]=pos[3*i+2];
            float rad = feat[7*i+1], sc = feat[7*i+2];
            float rho = rad - OFFSETC;
            sRho[tid]=rho; sSr[tid]=sc*rho;
            sI[tid]=0.f;
        }
        __syncthreads();
        int T = bb*256 + tid;
        int s = T >> 3, p = T & 7;
        int sl = s & 255;
        int e0 = s*32 + p*4;
        float px = sPx[sl], py = sPy[sl], pz = sPz[sl];
        float sr = sSr[sl];
        float srr = sr*sr;
        const int* dP = ei + EGB;
        int4 d4 = *(const int4*)(dP + e0);
        int dls[4] = {d4.x&255, d4.y&255, d4.z&255, d4.w&255};
#pragma unroll
        for (int j=0;j<4;j++){
            int dl = dls[j];
            float dx = px - sPx[dl];
            float dy = py - sPy[dl];
            float dz = pz - sPz[dl];
            float d2 = dx*dx+dy*dy+dz*dz + 1e-12f;
            float rd = frsq(d2);          // 1/d
            float d  = d2*rd;             // d
            float rho_i = sRho[dl];
            float U = d + sr;
            if (rho_i < U){
                float L = fmaxf(rho_i, fabsf(d - sr));
                float invU = frcp(U), invL = frcp(L);
                float I = 0.5f*invL - 0.5f*invU
                        + 0.125f*(d - srr*rd)*(invU*invU - invL*invL)
                        + 0.25f*__logf(L*invU)*rd;
                atomicAdd(&sI[dl], I);
            }
        }
        __syncthreads();
        atomicAdd(&Isum[mbase + tid], sI[tid]);
    } else {
        int e = (blockIdx.x-4672)*256 + tid;
        int s = gei[e], dd = gei[EGNN+e];
        float dx = pos[3*s+0] - pos[3*dd+0];
        float dy = pos[3*s+1] - pos[3*dd+1];
        float dz = pos[3*s+2] - pos[3*dd+2];
        dgnn[e] = fsqrt(dx*dx+dy*dy+dz*dz + 1e-12f);
        atomicAdd(&cnt[dd], 1);
    }
}

// ============ MEGA-B: gbB per-atom + scan + CSR fill (LDS cursor) ============
__global__ __launch_bounds__(256) void k_B(
    const float* __restrict__ feat, const float* __restrict__ Isum,
    float* __restrict__ Bv, float* __restrict__ cB, float* __restrict__ gB,
    float* __restrict__ egb,
    const int* __restrict__ cnt, int* __restrict__ rptr,
    const int* __restrict__ gei, const float* __restrict__ dgnn,
    int* __restrict__ csr, int2* __restrict__ csr2)
{
    int t = threadIdx.x;
    if (blockIdx.x < 64){
        int i = blockIdx.x*256 + t;
        float q   = feat[7*i+0];
        float rad = feat[7*i+1];
        float rho = rad - OFFSETC;
        float psi = Isum[i]*rho;
        float u = psi*(ALPHAC + psi*(-BETAC + GAMMAC*psi));
        float tt = tanhf(u);
        float rrad = frcp(rad);
        float B = frcp(frcp(rho) - tt*rrad);
        Bv[i] = B;
        float du = ALPHAC + psi*(-2.0f*BETAC + 3.0f*GAMMAC*psi);
        cB[i] = B*B*((1.0f-tt*tt)*rrad)*du*rho;
        float Cs = 0.5f*PREFC*q*q;
        float rB = frcp(B);
        egb[i] = Cs*rB;
        gB[i]  = -Cs*rB*rB;
    } else {
        __shared__ int sc[256];
        __shared__ int lcur[256];
        int m = blockIdx.x - 64;
        int c = cnt[m*256+t];
        sc[t] = c; __syncthreads();
        for (int off=1; off<256; off<<=1){
            int x = (t>=off) ? sc[t-off] : 0;
            __syncthreads();
            sc[t] += x;
            __syncthreads();
        }
        int exl = sc[t] - c;             // exclusive prefix, molecule-local
        rptr[m*256+t] = m*4096 + exl;
        lcur[t] = exl;
        __syncthreads();
        int e0 = m*4096;
        for (int j=t; j<4096; j+=256){
            int e = e0 + j;
            int dl = gei[EGNN+e] & 255;
            float d = dgnn[e];
            int p = atomicAdd(&lcur[dl], 1);
            int idx = e0 + p;
            csr[idx] = e;
            int2 rec; rec.x = (e >> 4) << 8;   // byte offset of src row (128 bf16)
            rec.y = __float_as_int(d);
            csr2[idx] = rec;
        }
    }
}

__global__ __launch_bounds__(256) void k_gbC(
    const float* __restrict__ pos, const float* __restrict__ feat,
    const int* __restrict__ ei, const float* __restrict__ Bv,
    float* __restrict__ egb, float* __restrict__ gdgb, float* __restrict__ gB)
{
    __shared__ float sPx[256], sPy[256], sPz[256], sB[256], sQf[256];
    __shared__ float sE[256], sG[256];
    int tid = threadIdx.x;
    int mbase = (blockIdx.x >> 3) * 256;
    {
        int i = mbase + tid;
        sPx[tid]=pos[3*i]; sPy[tid]=pos[3*i+1]; sPz[tid]=pos[3*i+2];
        sB[tid]=Bv[i]; sQf[tid]=feat[7*i+0];
        sE[tid]=0.f; sG[tid]=0.f;
    }
    __syncthreads();
    int T = blockIdx.x*256 + tid;
    int s = T >> 3, p = T & 7;
    int sl = s & 255;
    int e0 = s*32 + p*4;
    float px = sPx[sl], py = sPy[sl], pz = sPz[sl];
    float qs = sQf[sl];
    float Bs = sB[sl];
    float gsrc = 0.f;
    const int* dP = ei + EGB;
    int4 d4 = *(const int4*)(dP + e0);
    int dls[4] = {d4.x&255, d4.y&255, d4.z&255, d4.w&255};
#pragma unroll
    for (int j=0;j<4;j++){
        int dl = dls[j];
        float dx = px - sPx[dl];
        float dy = py - sPy[dl];
        float dz = pz - sPz[dl];
        float d2 = dx*dx+dy*dy+dz*dz + 1e-12f;
        float d  = d2*frsq(d2);
        float Bd = sB[dl];
        float C = 0.5f*PREFC*sQf[dl]*qs;
        float P = Bd*Bs;
        float qq = 0.25f*d2*frcp(P);
        float ex = __expf(-qq);
        float f2 = d2 + P*ex;
        float rf = frsq(f2);              // 1/f
        float f3i = rf*rf*rf;             // 1/f^3
        gdgb[e0+j] = -C*d*(1.f - 0.25f*ex)*f3i;
        float common = -C*ex*(1.f + qq)*0.5f*f3i;
        atomicAdd(&sE[dl], C*rf);
        atomicAdd(&sG[dl], common*Bs);
        gsrc += common*Bd;
    }
    gsrc += __shfl_xor(gsrc,1);
    gsrc += __shfl_xor(gsrc,2);
    gsrc += __shfl_xor(gsrc,4);
    if (p==0) atomicAdd(&sG[sl], gsrc);
    __syncthreads();
    atomicAdd(&egb[mbase + tid], sE[tid]);
    atomicAdd(&gB[mbase + tid],  sG[tid]);
}

__global__ __launch_bounds__(256) void k_gbE(
    const float* __restrict__ pos, const float* __restrict__ feat,
    const int* __restrict__ ei, const float* __restrict__ cB,
    const float* __restrict__ gB,
    const float* __restrict__ gdgb, float* __restrict__ grad)
{
    __shared__ float sPx[256], sPy[256], sPz[256], sRho[256], sSr[256], sCg[256];
    __shared__ float sGx[256], sGy[256], sGz[256];
    int tid = threadIdx.x;
    int mbase = (blockIdx.x >> 3) * 256;
    {
        int i = mbase + tid;
        sPx[tid]=pos[3*i]; sPy[tid]=pos[3*i+1]; sPz[tid]=pos[3*i+2];
        float rad = feat[7*i+1], sc = feat[7*i+2];
        float rho = rad - OFFSETC;
        sRho[tid]=rho; sSr[tid]=sc*rho;
        sCg[tid]=cB[i]*gB[i];
        sGx[tid]=0.f; sGy[tid]=0.f; sGz[tid]=0.f;
    }
    __syncthreads();
    int T = blockIdx.x*256 + tid;
    int s = T >> 3, p = T & 7;
    int sl = s & 255;
    int e0 = s*32 + p*4;
    float px = sPx[sl], py = sPy[sl], pz = sPz[sl];
    float sr = sSr[sl];
    float srr = sr*sr;
    float gx=0.f, gy=0.f, gz=0.f;
    const int* dP = ei + EGB;
    int4 d4 = *(const int4*)(dP + e0);
    int dls[4] = {d4.x&255, d4.y&255, d4.z&255, d4.w&255};
#pragma unroll
    for (int j=0;j<4;j++){
        int dl = dls[j];
        float dx = px - sPx[dl];
        float dy = py - sPy[dl];
        float dz = pz - sPz[dl];
        float d2 = dx*dx+dy*dy+dz*dz + 1e-12f;
        float rd = frsq(d2);              // 1/d
        float d  = d2*rd;
        float rd2 = rd*rd;                // 1/d2
        float rho_i = sRho[dl];
        float U = d + sr;
        float gd = gdgb[e0+j];
        if (rho_i < U){
            float aa = fabsf(d - sr);
            float L, Lp;
            if (rho_i >= aa){ L = rho_i; Lp = 0.f; }
            else { L = aa; Lp = (d >= sr) ? 1.f : -1.f; }
            float invU = frcp(U), invL = frcp(L);
            float invU2=invU*invU, invL2=invL*invL;
            float dIdd = -0.5f*Lp*invL2 + 0.5f*invU2
                + 0.125f*(1.f + srr*rd2)*(invU2 - invL2)
                + 0.125f*(d - srr*rd)*(2.f*Lp*invL2*invL - 2.f*invU2*invU)
                + 0.25f*((Lp*invL - invU)*rd - __logf(L*invU)*rd2);
            gd += sCg[dl]*dIdd;
        }
        float c = gd*rd;
        gx += c*dx; gy += c*dy; gz += c*dz;
        atomicAdd(&sGx[dl], -c*dx);
        atomicAdd(&sGy[dl], -c*dy);
        atomicAdd(&sGz[dl], -c*dz);
    }
    gx += __shfl_xor(gx,1); gx += __shfl_xor(gx,2); gx += __shfl_xor(gx,4);
    gy += __shfl_xor(gy,1); gy += __shfl_xor(gy,2); gy += __shfl_xor(gy,4);
    gz += __shfl_xor(gz,1); gz += __shfl_xor(gz,2); gz += __shfl_xor(gz,4);
    if (p==0){
        atomicAdd(&sGx[sl], gx);
        atomicAdd(&sGy[sl], gy);
        atomicAdd(&sGz[sl], gz);
    }
    __syncthreads();
    int i = mbase + tid;
    atomicAdd(&grad[3*i+0], sGx[tid]);
    atomicAdd(&grad[3*i+1], sGy[tid]);
    atomicAdd(&grad[3*i+2], sGz[tid]);
}

// ============ wave-per-node edge passes (no LDS, no barriers, 2 k per lane) ====

template<bool WSDS>
__device__ __forceinline__ void edge_fwd_wave(
    int dst, int lane,
    const int2* __restrict__ csr2, const int* __restrict__ rptr, const int* __restrict__ cnt,
    const uint* __restrict__ u, const uint* __restrict__ v,
    const float* __restrict__ wdp, const float* __restrict__ bb,
    uint* __restrict__ Hs, uint* __restrict__ Sds)
{
    int n = cnt[dst], r0 = rptr[dst];
    float2 wd = *(const float2*)&wdp[2*lane];
    float2 b2 = *(const float2*)&bb[2*lane];
    uint vp = v[dst*64 + lane];
    float base0 = lo2f(vp) + b2.x;
    float base1 = hi2f(vp) + b2.y;
    float h0=0.f,h1=0.f,e0a=0.f,e1a=0.f;
    for (int j0=0; j0<n; j0+=64){
        int m = n - j0; if (m > 64) m = 64;
        int rx = 0, ry = 0;
        if (lane < m){ int2 rc = csr2[r0+j0+lane]; rx = rc.x; ry = rc.y; }
#pragma unroll 2
        for (int j=0;j<m;j++){
            int off = __builtin_amdgcn_readlane(rx, j);
            float d  = __uint_as_float((unsigned)__builtin_amdgcn_readlane(ry, j));
            uint up = *(const uint*)((const char*)u + off + 4*lane);
            float a0 = fmaf(d, wd.x, base0 + lo2f(up));
            float a1 = fmaf(d, wd.y, base1 + hi2f(up));
            float s0 = sigf(a0), s1 = sigf(a1);
            float p0 = a0*s0, p1 = a1*s1;
            h0 += p0; h1 += p1;
            if (WSDS){
                e0a = fmaf(s0, 1.f + a0 - p0, e0a);
                e1a = fmaf(s1, 1.f + a1 - p1, e1a);
            }
        }
    }
    Hs[dst*64+lane] = pack2(h0,h1);
    if (WSDS) Sds[dst*64+lane] = pack2(e0a,e1a);
}

__global__ __launch_bounds__(256,8) void k_edge_fwd0(
    const int2* __restrict__ csr2, const int* __restrict__ rptr, const int* __restrict__ cnt,
    const uint* __restrict__ u, const uint* __restrict__ v,
    const float* __restrict__ wdp, const float* __restrict__ bb,
    uint* __restrict__ Hs)
{
    int lane = threadIdx.x & 63, wid = threadIdx.x >> 6;
    int dst = blockIdx.x*4 + wid;
    edge_fwd_wave<false>(dst, lane, csr2, rptr, cnt, u, v, wdp, bb, Hs, nullptr);
}

__global__ __launch_bounds__(256,8) void k_edge_fwd1(
    const int2* __restrict__ csr2, const int* __restrict__ rptr, const int* __restrict__ cnt,
    const uint* __restrict__ u, const uint* __restrict__ v,
    const float* __restrict__ wdp, const float* __restrict__ bb,
    uint* __restrict__ Hs, uint* __restrict__ Sds)
{
    int lane = threadIdx.x & 63, wid = threadIdx.x >> 6;
    int dst = blockIdx.x*4 + wid;
    edge_fwd_wave<true>(dst, lane, csr2, rptr, cnt, u, v, wdp, bb, Hs, Sds);
}

// l3: dst role computes Gd + x3; src role computes Gs + gdg  (fused launch)
__global__ __launch_bounds__(256,4) void k_l3(
    const int2* __restrict__ csr2, const int* __restrict__ rptr, const int* __restrict__ cnt,
    const int* __restrict__ gei, const float* __restrict__ dgnn,
    const uint* __restrict__ u, const uint* __restrict__ v,
    const float* __restrict__ A3, const float* __restrict__ B3,
    const float* __restrict__ C3, const float* __restrict__ D3,
    uint* __restrict__ Gd, float* __restrict__ x3,
    uint* __restrict__ Gs, float* __restrict__ gdg)
{
    int lane = threadIdx.x & 63, wid = threadIdx.x >> 6;
    const float* wdp = A3 + 256*HID;
    if (blockIdx.x < NATOMS/4){
        int dst = blockIdx.x*4 + wid;
        int n = cnt[dst], r0 = rptr[dst];
        float2 wd = *(const float2*)&wdp[2*lane];
        float2 b2 = *(const float2*)&B3[2*lane];
        float2 ck = *(const float2*)&C3[2*lane];
        uint vp = v[dst*64 + lane];
        float base0 = lo2f(vp) + b2.x;
        float base1 = hi2f(vp) + b2.y;
        float h0=0.f,h1=0.f,e0a=0.f,e1a=0.f;
        for (int j0=0; j0<n; j0+=64){
            int m = n - j0; if (m > 64) m = 64;
            int rx = 0, ry = 0;
            if (lane < m){ int2 rc = csr2[r0+j0+lane]; rx = rc.x; ry = rc.y; }
#pragma unroll 2
            for (int j=0;j<m;j++){
                int off = __builtin_amdgcn_readlane(rx, j);
                float d  = __uint_as_float((unsigned)__builtin_amdgcn_readlane(ry, j));
                uint up = *(const uint*)((const char*)u + off + 4*lane);
                float a0 = fmaf(d, wd.x, base0 + lo2f(up));
                float a1 = fmaf(d, wd.y, base1 + hi2f(up));
                float s0 = sigf(a0), s1 = sigf(a1);
                float p0 = a0*s0, p1 = a1*s1;
                h0 += p0; h1 += p1;
                e0a = fmaf(s0, 1.f + a0 - p0, e0a);
                e1a = fmaf(s1, 1.f + a1 - p1, e1a);
            }
        }
        Gd[dst*64+lane] = pack2(ck.x*e0a, ck.y*e1a);
        float px = waveRed(ck.x*h0 + ck.y*h1);
        if (lane==0) x3[dst] = px + (float)n*D3[0];
    } else {
        int s = (blockIdx.x - NATOMS/4)*4 + wid;
        int doff = 0, dbit = 0;
        if (lane < 16){
            doff = gei[EGNN + s*16 + lane] << 8;
            dbit = __float_as_int(dgnn[s*16+lane]);
        }
        float2 wd = *(const float2*)&wdp[2*lane];
        float2 b2 = *(const float2*)&B3[2*lane];
        float2 ck = *(const float2*)&C3[2*lane];
        uint up = u[s*64 + lane];
        float us0 = lo2f(up) + b2.x;
        float us1 = hi2f(up) + b2.y;
        float cw0 = ck.x*wd.x, cw1 = ck.y*wd.y;
        float gs0=0.f, gs1=0.f;
        float A[16];
#pragma unroll
        for (int t=0;t<16;t++){
            int off = __builtin_amdgcn_readlane(doff, t);
            float d = __uint_as_float((unsigned)__builtin_amdgcn_readlane(dbit, t));
            uint vp = *(const uint*)((const char*)v + off + 4*lane);
            float a0 = fmaf(d, wd.x, us0 + lo2f(vp));
            float a1 = fmaf(d, wd.y, us1 + hi2f(vp));
            float s0 = sigf(a0), s1 = sigf(a1);
            float p0 = a0*s0, p1 = a1*s1;
            float dv0 = s0*(1.f + a0 - p0);
            float dv1 = s1*(1.f + a1 - p1);
            gs0 += dv0; gs1 += dv1;
            A[t] = fmaf(dv1, cw1, dv0*cw0);
        }
        Gs[s*64+lane] = pack2(ck.x*gs0, ck.y*gs1);
        float tot = red16(A, lane);   // lane l holds edge (l>>1)&15
        if (lane < 32 && !(lane & 1)) gdg[s*16 + (lane>>1)] = tot;
    }
}

// backward src pass for layer 2 / layer 1: recompute dv, multiply by gH[dst]
__global__ __launch_bounds__(256,4) void k_bwd_src(
    const int* __restrict__ gei, const float* __restrict__ dgnn,
    const uint* __restrict__ u, const uint* __restrict__ v,
    const float* __restrict__ wdp, const float* __restrict__ bb,
    const uint* __restrict__ gH,
    uint* __restrict__ Gs, float* __restrict__ gdg)
{
    int lane = threadIdx.x & 63, wid = threadIdx.x >> 6;
    int s = blockIdx.x*4 + wid;
    int doff = 0, dbit = 0;
    if (lane < 16){
        doff = gei[EGNN + s*16 + lane] << 8;
        dbit = __float_as_int(dgnn[s*16+lane]);
    }
    float gold = gdg[s*16 + ((lane>>1)&15)];
    float2 wd = *(const float2*)&wdp[2*lane];
    float2 b2 = *(const float2*)&bb[2*lane];
    uint up = u[s*64 + lane];
    float us0 = lo2f(up) + b2.x;
    float us1 = hi2f(up) + b2.y;
    float gs0=0.f, gs1=0.f;
    float A[16];
#pragma unroll
    for (int t=0;t<16;t++){
        int off = __builtin_amdgcn_readlane(doff, t);
        float d = __uint_as_float((unsigned)__builtin_amdgcn_readlane(dbit, t));
        uint vp = *(const uint*)((const char*)v + off + 4*lane);
        uint gp = *(const uint*)((const char*)gH + off + 4*lane);
        float a0 = fmaf(d, wd.x, us0 + lo2f(vp));
        float a1 = fmaf(d, wd.y, us1 + hi2f(vp));
        float s0 = sigf(a0), s1 = sigf(a1);
        float p0 = a0*s0, p1 = a1*s1;
        float ga0 = s0*(1.f + a0 - p0) * lo2f(gp);
        float ga1 = s1*(1.f + a1 - p1) * hi2f(gp);
        gs0 += ga0; gs1 += ga1;
        A[t] = fmaf(ga1, wd.y, ga0*wd.x);
    }
    if (Gs) Gs[s*64+lane] = pack2(gs0, gs1);
    float tot = red16(A, lane);
    if (lane < 32 && !(lane & 1)) gdg[s*16 + (lane>>1)] = gold + tot;
}

// MFMA node forward
__global__ __launch_bounds__(256) void k_node_fwd_uv_mfma(
    const short* __restrict__ Hs, const int* __restrict__ cnt,
    const short* __restrict__ Ct, const float* __restrict__ D,
    const short* __restrict__ Aat, const short* __restrict__ Abt,
    bf* __restrict__ dsz, bf* __restrict__ u, bf* __restrict__ v)
{
    __shared__ short sx[64*HID];
    int lane = threadIdx.x & 63, w = threadIdx.x >> 6;
    int m0 = blockIdx.x*64 + w*16;
    int ar = lane & 15, kg = lane >> 4;
    bf8v af[4];
#pragma unroll
    for (int s=0;s<4;s++) af[s] = *(const bf8v*)&Hs[(size_t)(m0+ar)*HID + s*32 + kg*8];
    f4v acc[8];
#pragma unroll
    for (int nt=0;nt<8;nt++){
        acc[nt] = (f4v){0.f,0.f,0.f,0.f};
        const short* bp = Ct + (nt*16+ar)*HID + kg*8;
#pragma unroll
        for (int s=0;s<4;s++){
            bf8v bv = *(const bf8v*)(bp + s*32);
            acc[nt] = __builtin_amdgcn_mfma_f32_16x16x32_bf16(af[s], bv, acc[nt], 0,0,0);
        }
    }
    float cn[4];
#pragma unroll
    for (int r=0;r<4;r++) cn[r] = (float)cnt[m0 + kg*4 + r];
#pragma unroll
    for (int nt=0;nt<8;nt++){
        int j = nt*16 + ar;
        float Dj = D[j];
#pragma unroll
        for (int r=0;r<4;r++){
            int m = m0 + kg*4 + r;
            float zv = acc[nt][r] + cn[r]*Dj;
            float sg = sigf(zv);
            dsz[(size_t)m*HID + j] = f2b(sg*(1.f + zv*(1.f - sg)));
            sx[(w*16 + kg*4 + r)*HID + j] = f2s(zv*sg);
        }
    }
    __syncthreads();
#pragma unroll
    for (int s=0;s<4;s++) af[s] = *(const bf8v*)&sx[(w*16+ar)*HID + s*32 + kg*8];
    f4v au[8], av[8];
#pragma unroll
    for (int nt=0;nt<8;nt++){
        au[nt] = (f4v){0.f,0.f,0.f,0.f};
        av[nt] = (f4v){0.f,0.f,0.f,0.f};
        const short* bpa = Aat + (nt*16+ar)*HID + kg*8;
        const short* bpb = Abt + (nt*16+ar)*HID + kg*8;
#pragma unroll
        for (int s=0;s<4;s++){
            bf8v ba = *(const bf8v*)(bpa + s*32);
            bf8v bb = *(const bf8v*)(bpb + s*32);
            au[nt] = __builtin_amdgcn_mfma_f32_16x16x32_bf16(af[s], ba, au[nt], 0,0,0);
            av[nt] = __builtin_amdgcn_mfma_f32_16x16x32_bf16(af[s], bb, av[nt], 0,0,0);
        }
    }
#pragma unroll
    for (int nt=0;nt<8;nt++){
        int j = nt*16 + ar;
#pragma unroll
        for (int r=0;r<4;r++){
            int m = m0 + kg*4 + r;
            u[(size_t)m*HID + j] = f2b(au[nt][r]);
            v[(size_t)m*HID + j] = f2b(av[nt][r]);
        }
    }
}

// MFMA node backward. If Sds != nullptr: Gd frag = gHin ⊙ Sds.
__global__ __launch_bounds__(256) void k_gx_node_bwd_mfma(
    const short* __restrict__ Gs, const short* __restrict__ Gd,
    const short* __restrict__ gHin, const short* __restrict__ Sds,
    const short* __restrict__ Ra, const short* __restrict__ Rb,
    const bf* __restrict__ dsz, const short* __restrict__ Rc,
    bf* __restrict__ gHout)
{
    __shared__ short st[64*HID];
    int lane = threadIdx.x & 63, w = threadIdx.x >> 6;
    int m0 = blockIdx.x*64 + w*16;
    int ar = lane & 15, kg = lane >> 4;
    bf8v as_[4], ad_[4];
#pragma unroll
    for (int s=0;s<4;s++)
        as_[s] = *(const bf8v*)&Gs[(size_t)(m0+ar)*HID + s*32 + kg*8];
    if (Sds){
#pragma unroll
        for (int s=0;s<4;s++){
            bf8v g = *(const bf8v*)&gHin[(size_t)(m0+ar)*HID + s*32 + kg*8];
            bf8v sd = *(const bf8v*)&Sds[(size_t)(m0+ar)*HID + s*32 + kg*8];
            bf8v r;
#pragma unroll
            for (int i=0;i<8;i++) r[i] = f2s(s2f(g[i])*s2f(sd[i]));
            ad_[s] = r;
        }
    } else {
#pragma unroll
        for (int s=0;s<4;s++)
            ad_[s] = *(const bf8v*)&Gd[(size_t)(m0+ar)*HID + s*32 + kg*8];
    }
    f4v acc[8];
#pragma unroll
    for (int nt=0;nt<8;nt++){
        acc[nt] = (f4v){0.f,0.f,0.f,0.f};
        const short* bpa = Ra + (nt*16+ar)*HID + kg*8;
        const short* bpb = Rb + (nt*16+ar)*HID + kg*8;
#pragma unroll
        for (int s=0;s<4;s++){
            bf8v ba = *(const bf8v*)(bpa + s*32);
            bf8v bb = *(const bf8v*)(bpb + s*32);
            acc[nt] = __builtin_amdgcn_mfma_f32_16x16x32_bf16(as_[s], ba, acc[nt], 0,0,0);
            acc[nt] = __builtin_amdgcn_mfma_f32_16x16x32_bf16(ad_[s], bb, acc[nt], 0,0,0);
        }
    }
#pragma unroll
    for (int nt=0;nt<8;nt++){
        int j = nt*16 + ar;
#pragma unroll
        for (int r=0;r<4;r++){
            int m = m0 + kg*4 + r;
            float t = acc[nt][r] * b2f(dsz[(size_t)m*HID + j]);
            st[(w*16 + kg*4 + r)*HID + j] = f2s(t);
        }
    }
    __syncthreads();
    bf8v af[4];
#pragma unroll
    for (int s=0;s<4;s++) af[s] = *(const bf8v*)&st[(w*16+ar)*HID + s*32 + kg*8];
    f4v a2[8];
#pragma unroll
    for (int nt=0;nt<8;nt++){
        a2[nt] = (f4v){0.f,0.f,0.f,0.f};
        const short* bp = Rc + (nt*16+ar)*HID + kg*8;
#pragma unroll
        for (int s=0;s<4;s++){
            bf8v bc = *(const bf8v*)(bp + s*32);
            a2[nt] = __builtin_amdgcn_mfma_f32_16x16x32_bf16(af[s], bc, a2[nt], 0,0,0);
        }
    }
#pragma unroll
    for (int nt=0;nt<8;nt++){
        int j = nt*16 + ar;
#pragma unroll
        for (int r=0;r<4;r++){
            gHout[(size_t)(m0 + kg*4 + r)*HID + j] = f2b(a2[nt][r]);
        }
    }
}

// ============ fused outputs: forces + per-molecule energies ============
__global__ __launch_bounds__(256) void k_out(
    const float* __restrict__ pos, const int* __restrict__ gei,
    const int* __restrict__ csr, const int* __restrict__ rptr, const int* __restrict__ cnt,
    const float* __restrict__ dgnn, const float* __restrict__ gdg,
    const float* __restrict__ grad,
    const float* __restrict__ egb, const float* __restrict__ x3,
    float* __restrict__ out)
{
    int tid = threadIdx.x;
    if (blockIdx.x < 512){
        float* fout = out + MOLS;
        int T = blockIdx.x*256 + tid;
        int i = T >> 3, p = T & 7;
        float px = pos[3*i+0], py = pos[3*i+1], pz = pos[3*i+2];
        float ax=0.f, ay=0.f, az=0.f;
        for (int j=p;j<16;j+=8){
            int e = i*16 + j;
            int o = gei[EGNN+e];
            float c = gdg[e]*frcp(dgnn[e]);
            ax += c*(px - pos[3*o+0]);
            ay += c*(py - pos[3*o+1]);
            az += c*(pz - pos[3*o+2]);
        }
        int n = cnt[i], r0 = rptr[i];
        for (int j=p;j<n;j+=8){
            int e = csr[r0+j];
            int o = e >> 4;
            float c = gdg[e]*frcp(dgnn[e]);
            ax += c*(px - pos[3*o+0]);
            ay += c*(py - pos[3*o+1]);
            az += c*(pz - pos[3*o+2]);
        }
        ax += __shfl_xor(ax,1); ax += __shfl_xor(ax,2); ax += __shfl_xor(ax,4);
        ay += __shfl_xor(ay,1); ay += __shfl_xor(ay,2); ay += __shfl_xor(ay,4);
        az += __shfl_xor(az,1); az += __shfl_xor(az,2); az += __shfl_xor(az,4);
        if (p==0){
            fout[3*i+0] = -(grad[3*i+0] + ax);
            fout[3*i+1] = -(grad[3*i+1] + ay);
            fout[3*i+2] = -(grad[3*i+2] + az);
        }
    } else {
        __shared__ float red[4];
        int m = blockIdx.x - 512;
        int i = m*ATOMSM + tid;
        float en = egb[i] + x3[i];
        float v = waveRed(en);
        int wave = tid>>6, lane = tid&63;
        if (lane==0) red[wave] = v;
        __syncthreads();
        if (tid==0) out[m] = red[0]+red[1]+red[2]+red[3];
    }
}

extern "C" void kernel_launch(void* const* d_in, const int* in_sizes, int n_in,
                              void* d_out, int out_size, void* d_ws, size_t ws_size,
                              hipStream_t stream)
{
    const float* pos  = (const float*)d_in[0];
    const float* feat = (const float*)d_in[1];
    const int* ei  = (const int*)d_in[3];
    const int* gei = (const int*)d_in[4];
    const float* A1f = (const float*)d_in[5];  const float* B1f = (const float*)d_in[6];
    const float* C1f = (const float*)d_in[7];  const float* D1f = (const float*)d_in[8];
    const float* A2f = (const float*)d_in[9];  const float* B2f = (const float*)d_in[10];
    const float* C2f = (const float*)d_in[11]; const float* D2f = (const float*)d_in[12];
    const float* A3f = (const float*)d_in[13]; const float* B3f = (const float*)d_in[14];
    const float* C3f = (const float*)d_in[15]; const float* D3f = (const float*)d_in[16];

    float* w = (float*)d_ws;
    size_t off = 0;
    auto nxt = [&](size_t n)->float*{ float* p = w + off; off += (n + 255) & ~(size_t)255; return p; };
    // contiguous zero-init region: Isum | cnt | grad  (5*NATOMS floats)
    float* Isum = nxt(NATOMS);
    int*   cnt  = (int*)nxt(NATOMS);
    float* grad = nxt(3*NATOMS);
    float* Bv = nxt(NATOMS); float* cB = nxt(NATOMS);
    float* gB = nxt(NATOMS); float* egb = nxt(NATOMS); float* x3 = nxt(NATOMS);
    int*   rptr = (int*)nxt(NATOMS);
    int*   csr  = (int*)nxt(EGNN);
    int2*  csr2 = (int2*)nxt((size_t)EGNN*2);
    float* dgnn = nxt(EGNN); float* gdgnn = nxt(EGNN); float* gdgb = nxt(EGB);
    bf* dsz1 = (bf*)nxt(NH/2); bf* dsz2 = (bf*)nxt(NH/2);
    bf* Hs1 = (bf*)nxt(NH/2); bf* Hs2 = (bf*)nxt(NH/2);
    bf* Gs3 = (bf*)nxt(NH/2); bf* Gd3 = (bf*)nxt(NH/2);
    bf* Sds2 = (bf*)nxt(NH/2);
    bf* u1 = (bf*)nxt(NH/2); bf* v1 = (bf*)nxt(NH/2);
    bf* u2 = (bf*)nxt(NH/2); bf* v2 = (bf*)nxt(NH/2);
    bf* v3 = (bf*)nxt(NH/2);
    short* C1t  = (short*)nxt(8192); short* C2t  = (short*)nxt(8192);
    short* A2at = (short*)nxt(8192); short* A2bt = (short*)nxt(8192);
    short* A3at = (short*)nxt(8192); short* A3bt = (short*)nxt(8192);
    short* rA2a = (short*)nxt(8192); short* rA2b = (short*)nxt(8192);
    short* rA3a = (short*)nxt(8192); short* rA3b = (short*)nxt(8192);
    short* rC1  = (short*)nxt(8192); short* rC2  = (short*)nxt(8192);
    // aliases:
    bf* u3  = Hs1;      // Hs1 dead after node_fwd #1
    bf* gH2 = Hs2;      // Hs2 dead after node_fwd #2
    bf* Gs2 = Gs3;      // dead after gx_node_bwd(3->2)
    bf* gH1 = u3;       // u3 dead after l3 kernel

    // single combined zero-init (Isum|cnt|grad are contiguous)
    hipMemsetAsync(Isum, 0, (size_t)5*NATOMS*sizeof(float), stream);

    // MEGA-A: weights + uv1 + gbA + dist
    k_A<<<64 + NH/512 + 512 + EGNN/256, 256, 0, stream>>>(
        A2f, C1f, A3f, C2f,
        C1t, C2t, A2at, A2bt, A3at, A3bt, rA2a, rA2b, rA3a, rA3b, rC1, rC2,
        feat, A1f, u1, v1,
        pos, ei, Isum, gei, dgnn, cnt);

    // MEGA-B: gbB + scan + fill (LDS cursors)
    k_B<<<128,256,0,stream>>>(feat, Isum, Bv, cB, gB, egb, cnt, rptr,
                              gei, dgnn, csr, csr2);

    // forward layer 1 (wave-per-dst, no Sds)
    k_edge_fwd0<<<NATOMS/4,256,0,stream>>>(csr2, rptr, cnt, (const uint*)u1, (const uint*)v1,
                                           A1f+4*HID, B1f, (uint*)Hs1);
    k_gbC<<<512,256,0,stream>>>(pos, feat, ei, Bv, egb, gdgb, gB);
    k_node_fwd_uv_mfma<<<NATOMS/64,256,0,stream>>>((const short*)Hs1, cnt, C1t, D1f,
                                                   A2at, A2bt, dsz1, u2, v2);
    // forward layer 2
    k_edge_fwd1<<<NATOMS/4,256,0,stream>>>(csr2, rptr, cnt, (const uint*)u2, (const uint*)v2,
                                           A2f+256*HID, B2f, (uint*)Hs2, (uint*)Sds2);
    k_gbE<<<512,256,0,stream>>>(pos, feat, ei, cB, gB, gdgb, grad);
    k_node_fwd_uv_mfma<<<NATOMS/64,256,0,stream>>>((const short*)Hs2, cnt, C2t, D2f,
                                                   A3at, A3bt, dsz2, u3, v3);

    // layer-3 fused dst+src (wave-per-node)
    k_l3<<<2*(NATOMS/4),256,0,stream>>>(csr2, rptr, cnt, gei, dgnn,
                                        (const uint*)u3, (const uint*)v3,
                                        A3f, B3f, C3f, D3f,
                                        (uint*)Gd3, x3, (uint*)Gs3, gdgnn);

    // backward chain
    k_gx_node_bwd_mfma<<<NATOMS/64,256,0,stream>>>((const short*)Gs3, (const short*)Gd3,
        (const short*)nullptr, (const short*)nullptr, rA3a, rA3b, dsz2, rC2, gH2);
    k_bwd_src<<<NATOMS/4,256,0,stream>>>(gei, dgnn, (const uint*)u2, (const uint*)v2,
                                         A2f+256*HID, B2f, (const uint*)gH2,
                                         (uint*)Gs2, gdgnn);
    k_gx_node_bwd_mfma<<<NATOMS/64,256,0,stream>>>((const short*)Gs2, (const short*)nullptr,
        (const short*)gH2, (const short*)Sds2, rA2a, rA2b, dsz1, rC1, gH1);
    k_bwd_src<<<NATOMS/4,256,0,stream>>>(gei, dgnn, (const uint*)u1, (const uint*)v1,
                                         A1f+4*HID, B1f, (const uint*)gH1,
                                         (uint*)nullptr, gdgnn);

    // fused outputs (forces + energies)
    k_out<<<576,256,0,stream>>>(pos, gei, csr, rptr, cnt, dgnn, gdgnn,
                                grad, egb, x3, (float*)d_out);
}

// Round 5
// 310.898 us; speedup vs baseline: 1.3202x; 1.0579x over previous
//
#include <hip/hip_runtime.h>
#include <hip/hip_bf16.h>

#define NATOMS 16384
#define MOLS   64
#define ATOMSM 256
#define EGB    524288
#define EGNN   262144
#define HID    128
#define NH     (NATOMS*HID)

#define OFFSETC 0.009f
#define ALPHAC  1.0f
#define BETAC   0.8f
#define GAMMAC  4.85f
#define PREFC   (-138.935456f*(1.0f-1.0f/78.5f))

typedef __hip_bfloat16 bf;
typedef __attribute__((ext_vector_type(8))) short bf8v;
typedef __attribute__((ext_vector_type(4))) float f4v;
typedef unsigned int uint;

__device__ __forceinline__ float b2f(bf x){ return __bfloat162float(x); }
__device__ __forceinline__ bf f2b(float x){ return __float2bfloat16(x); }
__device__ __forceinline__ short f2s(float x){ bf h = f2b(x); return *(short*)&h; }
__device__ __forceinline__ float s2f(short s){
    unsigned int x = ((unsigned int)(unsigned short)s) << 16;
    return __uint_as_float(x);
}
__device__ __forceinline__ float frcp(float x){ return __builtin_amdgcn_rcpf(x); }
__device__ __forceinline__ float frsq(float x){ return __builtin_amdgcn_rsqf(x); }
__device__ __forceinline__ float fsqrt(float x){ return __builtin_amdgcn_sqrtf(x); }
// fast sigmoid: v_mul+v_exp+v_add+v_rcp (avoids IEEE div sequence; -O3 has no fast-math)
__device__ __forceinline__ float sigf(float x){ return frcp(1.0f+__expf(-x)); }
__device__ __forceinline__ float waveRed(float v){
    v += __shfl_xor(v,32); v += __shfl_xor(v,16); v += __shfl_xor(v,8);
    v += __shfl_xor(v,4);  v += __shfl_xor(v,2);  v += __shfl_xor(v,1);
    return v;
}
__device__ __forceinline__ uint pack2(float a, float b){
    return (uint)(unsigned short)f2s(a) | ((uint)(unsigned short)f2s(b) << 16);
}
__device__ __forceinline__ float lo2f(uint w){ return __uint_as_float(w << 16); }
__device__ __forceinline__ float hi2f(uint w){ return __uint_as_float(w & 0xffff0000u); }

// butterfly reduction of 16 independent sums across 64 lanes.
// post: lane l holds total of A[(l>>1)&15] (17 shuffles vs 96 for per-edge waveRed).
__device__ __forceinline__ float red16(float (&A)[16], int lane){
#pragma unroll
    for (int i=0;i<8;i++){
        float send = (lane & 16) ? A[i] : A[i+8];
        float recv = __shfl_xor(send, 16);
        A[i] = ((lane & 16) ? A[i+8] : A[i]) + recv;
    }
#pragma unroll
    for (int i=0;i<4;i++){
        float send = (lane & 8) ? A[i] : A[i+4];
        float recv = __shfl_xor(send, 8);
        A[i] = ((lane & 8) ? A[i+4] : A[i]) + recv;
    }
#pragma unroll
    for (int i=0;i<2;i++){
        float send = (lane & 4) ? A[i] : A[i+2];
        float recv = __shfl_xor(send, 4);
        A[i] = ((lane & 4) ? A[i+2] : A[i]) + recv;
    }
    {
        float send = (lane & 2) ? A[0] : A[1];
        float recv = __shfl_xor(send, 2);
        A[0] = ((lane & 2) ? A[1] : A[0]) + recv;
    }
    A[0] += __shfl_xor(A[0], 32);
    A[0] += __shfl_xor(A[0], 1);
    return A[0];
}

// ============ MEGA-A: weight prep + uv1 + gbA + gnn-dist ============
__global__ __launch_bounds__(256) void k_A(
    const float* __restrict__ A2, const float* __restrict__ C1,
    const float* __restrict__ A3, const float* __restrict__ C2,
    short* __restrict__ C1t, short* __restrict__ C2t,
    short* __restrict__ A2at, short* __restrict__ A2bt,
    short* __restrict__ A3at, short* __restrict__ A3bt,
    short* __restrict__ rA2a, short* __restrict__ rA2b,
    short* __restrict__ rA3a, short* __restrict__ rA3b,
    short* __restrict__ rC1, short* __restrict__ rC2,
    const float* __restrict__ feat, const float* __restrict__ A1,
    bf* __restrict__ u1, bf* __restrict__ v1,
    const float* __restrict__ pos, const int* __restrict__ ei,
    float* __restrict__ Isum,
    const int* __restrict__ gei, float* __restrict__ dgnn, int* __restrict__ cnt)
{
    int tid = threadIdx.x;
    if (blockIdx.x < 64){
        int gid = blockIdx.x*256 + tid;
        int j = gid >> 7, k = gid & 127;
        C1t[gid]  = f2s(C1[k*HID+j]);
        C2t[gid]  = f2s(C2[k*HID+j]);
        A2at[gid] = f2s(A2[k*HID+j]);
        A2bt[gid] = f2s(A2[(HID+k)*HID+j]);
        A3at[gid] = f2s(A3[k*HID+j]);
        A3bt[gid] = f2s(A3[(HID+k)*HID+j]);
        rA2a[gid] = f2s(A2[gid]);
        rA2b[gid] = f2s(A2[HID*HID+gid]);
        rA3a[gid] = f2s(A3[gid]);
        rA3b[gid] = f2s(A3[HID*HID+gid]);
        rC1[gid]  = f2s(C1[gid]);
        rC2[gid]  = f2s(C2[gid]);
    } else if (blockIdx.x < 4160){
        int gid2 = (blockIdx.x-64)*256 + tid;   // [0, NH/2)
        int i = gid2 >> 6, k2 = (gid2 & 63)*2;
        float q = feat[7*i+0], r = feat[7*i+1];
        float u0 = q*A1[k2]         + r*A1[HID+k2];
        float u1v= q*A1[k2+1]       + r*A1[HID+k2+1];
        float v0 = q*A1[2*HID+k2]   + r*A1[3*HID+k2];
        float v1v= q*A1[2*HID+k2+1] + r*A1[3*HID+k2+1];
        ushort2 uu, vv;
        uu.x = (unsigned short)f2s(u0); uu.y = (unsigned short)f2s(u1v);
        vv.x = (unsigned short)f2s(v0); vv.y = (unsigned short)f2s(v1v);
        *(ushort2*)((short*)u1 + (size_t)i*HID + k2) = uu;
        *(ushort2*)((short*)v1 + (size_t)i*HID + k2) = vv;
    } else if (blockIdx.x < 4672){
        __shared__ float sPx[256], sPy[256], sPz[256], sRho[256], sSr[256];
        __shared__ float sI[256];
        int bb = blockIdx.x - 4160;
        int mbase = (bb >> 3) * 256;
        {
            int i = mbase + tid;
            sPx[tid]=pos[3*i]; sPy[tid]=pos[3*i+1]; sPz[tid]=pos[3*i+2];
            float rad = feat[7*i+1], sc = feat[7*i+2];
            float rho = rad - OFFSETC;
            sRho[tid]=rho; sSr[tid]=sc*rho;
            sI[tid]=0.f;
        }
        __syncthreads();
        int T = bb*256 + tid;
        int s = T >> 3, p = T & 7;
        int sl = s & 255;
        int e0 = s*32 + p*4;
        float px = sPx[sl], py = sPy[sl], pz = sPz[sl];
        float sr = sSr[sl];
        float srr = sr*sr;
        const int* dP = ei + EGB;
        int4 d4 = *(const int4*)(dP + e0);
        int dls[4] = {d4.x&255, d4.y&255, d4.z&255, d4.w&255};
#pragma unroll
        for (int j=0;j<4;j++){
            int dl = dls[j];
            float dx = px - sPx[dl];
            float dy = py - sPy[dl];
            float dz = pz - sPz[dl];
            float d2 = dx*dx+dy*dy+dz*dz + 1e-12f;
            float rd = frsq(d2);          // 1/d
            float d  = d2*rd;             // d
            float rho_i = sRho[dl];
            float U = d + sr;
            if (rho_i < U){
                float L = fmaxf(rho_i, fabsf(d - sr));
                float invU = frcp(U), invL = frcp(L);
                float I = 0.5f*invL - 0.5f*invU
                        + 0.125f*(d - srr*rd)*(invU*invU - invL*invL)
                        + 0.25f*__logf(L*invU)*rd;
                atomicAdd(&sI[dl], I);
            }
        }
        __syncthreads();
        atomicAdd(&Isum[mbase + tid], sI[tid]);
    } else {
        int e = (blockIdx.x-4672)*256 + tid;
        int s = gei[e], dd = gei[EGNN+e];
        float dx = pos[3*s+0] - pos[3*dd+0];
        float dy = pos[3*s+1] - pos[3*dd+1];
        float dz = pos[3*s+2] - pos[3*dd+2];
        dgnn[e] = fsqrt(dx*dx+dy*dy+dz*dz + 1e-12f);
        atomicAdd(&cnt[dd], 1);
    }
}

// ============ MEGA-B: gbB per-atom + scan + CSR fill (LDS cursor) ============
__global__ __launch_bounds__(256) void k_B(
    const float* __restrict__ feat, const float* __restrict__ Isum,
    float* __restrict__ Bv, float* __restrict__ cB, float* __restrict__ gB,
    float* __restrict__ egb,
    const int* __restrict__ cnt, int* __restrict__ rptr,
    const int* __restrict__ gei, const float* __restrict__ dgnn,
    int* __restrict__ csr, int2* __restrict__ csr2)
{
    int t = threadIdx.x;
    if (blockIdx.x < 64){
        int i = blockIdx.x*256 + t;
        float q   = feat[7*i+0];
        float rad = feat[7*i+1];
        float rho = rad - OFFSETC;
        float psi = Isum[i]*rho;
        float u = psi*(ALPHAC + psi*(-BETAC + GAMMAC*psi));
        float tt = tanhf(u);
        float rrad = frcp(rad);
        float B = frcp(frcp(rho) - tt*rrad);
        Bv[i] = B;
        float du = ALPHAC + psi*(-2.0f*BETAC + 3.0f*GAMMAC*psi);
        cB[i] = B*B*((1.0f-tt*tt)*rrad)*du*rho;
        float Cs = 0.5f*PREFC*q*q;
        float rB = frcp(B);
        egb[i] = Cs*rB;
        gB[i]  = -Cs*rB*rB;
    } else {
        __shared__ int sc[256];
        __shared__ int lcur[256];
        int m = blockIdx.x - 64;
        int c = cnt[m*256+t];
        sc[t] = c; __syncthreads();
        for (int off=1; off<256; off<<=1){
            int x = (t>=off) ? sc[t-off] : 0;
            __syncthreads();
            sc[t] += x;
            __syncthreads();
        }
        int exl = sc[t] - c;             // exclusive prefix, molecule-local
        rptr[m*256+t] = m*4096 + exl;
        lcur[t] = exl;
        __syncthreads();
        int e0 = m*4096;
        for (int j=t; j<4096; j+=256){
            int e = e0 + j;
            int dl = gei[EGNN+e] & 255;
            float d = dgnn[e];
            int p = atomicAdd(&lcur[dl], 1);
            int idx = e0 + p;
            csr[idx] = e;
            int2 rec; rec.x = (e >> 4) << 8;   // byte offset of src row (128 bf16)
            rec.y = __float_as_int(d);
            csr2[idx] = rec;
        }
    }
}

// ============ wave-per-node edge forward (no LDS, no barriers, 2 k per lane) ====
template<bool WSDS>
__device__ __forceinline__ void edge_fwd_wave(
    int dst, int lane,
    const int2* __restrict__ csr2, const int* __restrict__ rptr, const int* __restrict__ cnt,
    const uint* __restrict__ u, const uint* __restrict__ v,
    const float* __restrict__ wdp, const float* __restrict__ bb,
    uint* __restrict__ Hs, uint* __restrict__ Sds)
{
    int n = cnt[dst], r0 = rptr[dst];
    float2 wd = *(const float2*)&wdp[2*lane];
    float2 b2 = *(const float2*)&bb[2*lane];
    uint vp = v[dst*64 + lane];
    float base0 = lo2f(vp) + b2.x;
    float base1 = hi2f(vp) + b2.y;
    const char* ub = (const char*)u + 4*lane;
    float h0=0.f,h1=0.f,e0a=0.f,e1a=0.f;
    for (int j0=0; j0<n; j0+=64){
        int m = n - j0; if (m > 64) m = 64;
        int rx = 0, ry = 0;
        if (lane < m){ int2 rc = csr2[r0+j0+lane]; rx = rc.x; ry = rc.y; }
#pragma unroll 4
        for (int j=0;j<m;j++){
            int off = __builtin_amdgcn_readlane(rx, j);
            float d  = __uint_as_float((unsigned)__builtin_amdgcn_readlane(ry, j));
            uint up = *(const uint*)(ub + off);
            float a0 = fmaf(d, wd.x, base0 + lo2f(up));
            float a1 = fmaf(d, wd.y, base1 + hi2f(up));
            float s0 = sigf(a0), s1 = sigf(a1);
            float p0 = a0*s0, p1 = a1*s1;
            h0 += p0; h1 += p1;
            if (WSDS){
                e0a = fmaf(s0, 1.f + a0 - p0, e0a);
                e1a = fmaf(s1, 1.f + a1 - p1, e1a);
            }
        }
    }
    Hs[dst*64+lane] = pack2(h0,h1);
    if (WSDS) Sds[dst*64+lane] = pack2(e0a,e1a);
}

// ============ fused launch: gbC (blocks [0,512)) + edge_fwd layer1 (rest) ======
__global__ __launch_bounds__(256,8) void k_ef0C(
    // gbC args
    const float* __restrict__ pos, const float* __restrict__ feat,
    const int* __restrict__ ei, const float* __restrict__ Bv,
    float* __restrict__ egb, float* __restrict__ gdgb, float* __restrict__ gB,
    // ef0 args
    const int2* __restrict__ csr2, const int* __restrict__ rptr, const int* __restrict__ cnt,
    const uint* __restrict__ u, const uint* __restrict__ v,
    const float* __restrict__ wdp, const float* __restrict__ bb,
    uint* __restrict__ Hs)
{
    int tid = threadIdx.x;
    if (blockIdx.x < 512){
        __shared__ float sPx[256], sPy[256], sPz[256], sB[256], sQf[256];
        __shared__ float sE[256], sG[256];
        int mbase = (blockIdx.x >> 3) * 256;
        {
            int i = mbase + tid;
            sPx[tid]=pos[3*i]; sPy[tid]=pos[3*i+1]; sPz[tid]=pos[3*i+2];
            sB[tid]=Bv[i]; sQf[tid]=feat[7*i+0];
            sE[tid]=0.f; sG[tid]=0.f;
        }
        __syncthreads();
        int T = blockIdx.x*256 + tid;
        int s = T >> 3, p = T & 7;
        int sl = s & 255;
        int e0 = s*32 + p*4;
        float px = sPx[sl], py = sPy[sl], pz = sPz[sl];
        float qs = sQf[sl];
        float Bs = sB[sl];
        float gsrc = 0.f;
        const int* dP = ei + EGB;
        int4 d4 = *(const int4*)(dP + e0);
        int dls[4] = {d4.x&255, d4.y&255, d4.z&255, d4.w&255};
#pragma unroll
        for (int j=0;j<4;j++){
            int dl = dls[j];
            float dx = px - sPx[dl];
            float dy = py - sPy[dl];
            float dz = pz - sPz[dl];
            float d2 = dx*dx+dy*dy+dz*dz + 1e-12f;
            float d  = d2*frsq(d2);
            float Bd = sB[dl];
            float C = 0.5f*PREFC*sQf[dl]*qs;
            float P = Bd*Bs;
            float qq = 0.25f*d2*frcp(P);
            float ex = __expf(-qq);
            float f2 = d2 + P*ex;
            float rf = frsq(f2);              // 1/f
            float f3i = rf*rf*rf;             // 1/f^3
            gdgb[e0+j] = -C*d*(1.f - 0.25f*ex)*f3i;
            float common = -C*ex*(1.f + qq)*0.5f*f3i;
            atomicAdd(&sE[dl], C*rf);
            atomicAdd(&sG[dl], common*Bs);
            gsrc += common*Bd;
        }
        gsrc += __shfl_xor(gsrc,1);
        gsrc += __shfl_xor(gsrc,2);
        gsrc += __shfl_xor(gsrc,4);
        if (p==0) atomicAdd(&sG[sl], gsrc);
        __syncthreads();
        atomicAdd(&egb[mbase + tid], sE[tid]);
        atomicAdd(&gB[mbase + tid],  sG[tid]);
    } else {
        int lane = tid & 63, wid = tid >> 6;
        int dst = (blockIdx.x-512)*4 + wid;
        edge_fwd_wave<false>(dst, lane, csr2, rptr, cnt, u, v, wdp, bb, Hs, nullptr);
    }
}

// layer-2 forward (standalone)
__global__ __launch_bounds__(256,8) void k_edge_fwd1(
    const int2* __restrict__ csr2, const int* __restrict__ rptr, const int* __restrict__ cnt,
    const uint* __restrict__ u, const uint* __restrict__ v,
    const float* __restrict__ wdp, const float* __restrict__ bb,
    uint* __restrict__ Hs, uint* __restrict__ Sds)
{
    int lane = threadIdx.x & 63, wid = threadIdx.x >> 6;
    int dst = blockIdx.x*4 + wid;
    edge_fwd_wave<true>(dst, lane, csr2, rptr, cnt, u, v, wdp, bb, Hs, Sds);
}

// node forward body (MFMA), used by merged kernel
__device__ __forceinline__ void node_fwd_body(
    int blk, int tid,
    const short* __restrict__ Hs, const int* __restrict__ cnt,
    const short* __restrict__ Ct, const float* __restrict__ D,
    const short* __restrict__ Aat, const short* __restrict__ Abt,
    bf* __restrict__ dsz, bf* __restrict__ u, bf* __restrict__ v,
    short* sx)
{
    int lane = tid & 63, w = tid >> 6;
    int m0 = blk*64 + w*16;
    int ar = lane & 15, kg = lane >> 4;
    bf8v af[4];
#pragma unroll
    for (int s=0;s<4;s++) af[s] = *(const bf8v*)&Hs[(size_t)(m0+ar)*HID + s*32 + kg*8];
    f4v acc[8];
#pragma unroll
    for (int nt=0;nt<8;nt++){
        acc[nt] = (f4v){0.f,0.f,0.f,0.f};
        const short* bp = Ct + (nt*16+ar)*HID + kg*8;
#pragma unroll
        for (int s=0;s<4;s++){
            bf8v bv = *(const bf8v*)(bp + s*32);
            acc[nt] = __builtin_amdgcn_mfma_f32_16x16x32_bf16(af[s], bv, acc[nt], 0,0,0);
        }
    }
    float cn[4];
#pragma unroll
    for (int r=0;r<4;r++) cn[r] = (float)cnt[m0 + kg*4 + r];
#pragma unroll
    for (int nt=0;nt<8;nt++){
        int j = nt*16 + ar;
        float Dj = D[j];
#pragma unroll
        for (int r=0;r<4;r++){
            int m = m0 + kg*4 + r;
            float zv = acc[nt][r] + cn[r]*Dj;
            float sg = sigf(zv);
            dsz[(size_t)m*HID + j] = f2b(sg*(1.f + zv*(1.f - sg)));
            sx[(w*16 + kg*4 + r)*HID + j] = f2s(zv*sg);
        }
    }
    __syncthreads();
#pragma unroll
    for (int s=0;s<4;s++) af[s] = *(const bf8v*)&sx[(w*16+ar)*HID + s*32 + kg*8];
    f4v au[8], av[8];
#pragma unroll
    for (int nt=0;nt<8;nt++){
        au[nt] = (f4v){0.f,0.f,0.f,0.f};
        av[nt] = (f4v){0.f,0.f,0.f,0.f};
        const short* bpa = Aat + (nt*16+ar)*HID + kg*8;
        const short* bpb = Abt + (nt*16+ar)*HID + kg*8;
#pragma unroll
        for (int s=0;s<4;s++){
            bf8v ba = *(const bf8v*)(bpa + s*32);
            bf8v bb = *(const bf8v*)(bpb + s*32);
            au[nt] = __builtin_amdgcn_mfma_f32_16x16x32_bf16(af[s], ba, au[nt], 0,0,0);
            av[nt] = __builtin_amdgcn_mfma_f32_16x16x32_bf16(af[s], bb, av[nt], 0,0,0);
        }
    }
#pragma unroll
    for (int nt=0;nt<8;nt++){
        int j = nt*16 + ar;
#pragma unroll
        for (int r=0;r<4;r++){
            int m = m0 + kg*4 + r;
            u[(size_t)m*HID + j] = f2b(au[nt][r]);
            v[(size_t)m*HID + j] = f2b(av[nt][r]);
        }
    }
}

// ============ fused launch: gbE (blocks [0,512)) + node_fwd layer1 (rest) ======
__global__ __launch_bounds__(256,4) void k_nf1E(
    // gbE args
    const float* __restrict__ pos, const float* __restrict__ feat,
    const int* __restrict__ ei, const float* __restrict__ cB,
    const float* __restrict__ gB,
    const float* __restrict__ gdgb, float* __restrict__ grad,
    // node fwd args
    const short* __restrict__ Hs, const int* __restrict__ cnt,
    const short* __restrict__ Ct, const float* __restrict__ D,
    const short* __restrict__ Aat, const short* __restrict__ Abt,
    bf* __restrict__ dsz, bf* __restrict__ u, bf* __restrict__ v)
{
    __shared__ short sx[64*HID];   // 16 KB; gbE path reuses a slice as float buffers
    int tid = threadIdx.x;
    if (blockIdx.x < 512){
        float* sPx = (float*)sx;           // 6 float arrays of 256 = 6 KB
        float* sPy = sPx + 256;
        float* sPz = sPy + 256;
        float* sRho = sPz + 256;
        float* sSr = sRho + 256;
        float* sCg = sSr + 256;
        __shared__ float sGx[256], sGy[256], sGz[256];
        int mbase = (blockIdx.x >> 3) * 256;
        {
            int i = mbase + tid;
            sPx[tid]=pos[3*i]; sPy[tid]=pos[3*i+1]; sPz[tid]=pos[3*i+2];
            float rad = feat[7*i+1], sc = feat[7*i+2];
            float rho = rad - OFFSETC;
            sRho[tid]=rho; sSr[tid]=sc*rho;
            sCg[tid]=cB[i]*gB[i];
            sGx[tid]=0.f; sGy[tid]=0.f; sGz[tid]=0.f;
        }
        __syncthreads();
        int T = blockIdx.x*256 + tid;
        int s = T >> 3, p = T & 7;
        int sl = s & 255;
        int e0 = s*32 + p*4;
        float px = sPx[sl], py = sPy[sl], pz = sPz[sl];
        float sr = sSr[sl];
        float srr = sr*sr;
        float gx=0.f, gy=0.f, gz=0.f;
        const int* dP = ei + EGB;
        int4 d4 = *(const int4*)(dP + e0);
        int dls[4] = {d4.x&255, d4.y&255, d4.z&255, d4.w&255};
#pragma unroll
        for (int j=0;j<4;j++){
            int dl = dls[j];
            float dx = px - sPx[dl];
            float dy = py - sPy[dl];
            float dz = pz - sPz[dl];
            float d2 = dx*dx+dy*dy+dz*dz + 1e-12f;
            float rd = frsq(d2);              // 1/d
            float d  = d2*rd;
            float rd2 = rd*rd;                // 1/d2
            float rho_i = sRho[dl];
            float U = d + sr;
            float gd = gdgb[e0+j];
            if (rho_i < U){
                float aa = fabsf(d - sr);
                float L, Lp;
                if (rho_i >= aa){ L = rho_i; Lp = 0.f; }
                else { L = aa; Lp = (d >= sr) ? 1.f : -1.f; }
                float invU = frcp(U), invL = frcp(L);
                float invU2=invU*invU, invL2=invL*invL;
                float dIdd = -0.5f*Lp*invL2 + 0.5f*invU2
                    + 0.125f*(1.f + srr*rd2)*(invU2 - invL2)
                    + 0.125f*(d - srr*rd)*(2.f*Lp*invL2*invL - 2.f*invU2*invU)
                    + 0.25f*((Lp*invL - invU)*rd - __logf(L*invU)*rd2);
                gd += sCg[dl]*dIdd;
            }
            float c = gd*rd;
            gx += c*dx; gy += c*dy; gz += c*dz;
            atomicAdd(&sGx[dl], -c*dx);
            atomicAdd(&sGy[dl], -c*dy);
            atomicAdd(&sGz[dl], -c*dz);
        }
        gx += __shfl_xor(gx,1); gx += __shfl_xor(gx,2); gx += __shfl_xor(gx,4);
        gy += __shfl_xor(gy,1); gy += __shfl_xor(gy,2); gy += __shfl_xor(gy,4);
        gz += __shfl_xor(gz,1); gz += __shfl_xor(gz,2); gz += __shfl_xor(gz,4);
        if (p==0){
            atomicAdd(&sGx[sl], gx);
            atomicAdd(&sGy[sl], gy);
            atomicAdd(&sGz[sl], gz);
        }
        __syncthreads();
        int i = mbase + tid;
        atomicAdd(&grad[3*i+0], sGx[tid]);
        atomicAdd(&grad[3*i+1], sGy[tid]);
        atomicAdd(&grad[3*i+2], sGz[tid]);
    } else {
        node_fwd_body(blockIdx.x-512, tid, Hs, cnt, Ct, D, Aat, Abt, dsz, u, v, sx);
    }
}

// standalone node forward (layer 2)
__global__ __launch_bounds__(256) void k_node_fwd_uv_mfma(
    const short* __restrict__ Hs, const int* __restrict__ cnt,
    const short* __restrict__ Ct, const float* __restrict__ D,
    const short* __restrict__ Aat, const short* __restrict__ Abt,
    bf* __restrict__ dsz, bf* __restrict__ u, bf* __restrict__ v)
{
    __shared__ short sx[64*HID];
    node_fwd_body(blockIdx.x, threadIdx.x, Hs, cnt, Ct, D, Aat, Abt, dsz, u, v, sx);
}

// l3: dst role computes Gd + x3; src role computes Gs + gdg  (fused launch)
__global__ __launch_bounds__(256,4) void k_l3(
    const int2* __restrict__ csr2, const int* __restrict__ rptr, const int* __restrict__ cnt,
    const int* __restrict__ gei, const float* __restrict__ dgnn,
    const uint* __restrict__ u, const uint* __restrict__ v,
    const float* __restrict__ A3, const float* __restrict__ B3,
    const float* __restrict__ C3, const float* __restrict__ D3,
    uint* __restrict__ Gd, float* __restrict__ x3,
    uint* __restrict__ Gs, float* __restrict__ gdg)
{
    int lane = threadIdx.x & 63, wid = threadIdx.x >> 6;
    const float* wdp = A3 + 256*HID;
    if (blockIdx.x < NATOMS/4){
        int dst = blockIdx.x*4 + wid;
        int n = cnt[dst], r0 = rptr[dst];
        float2 wd = *(const float2*)&wdp[2*lane];
        float2 b2 = *(const float2*)&B3[2*lane];
        float2 ck = *(const float2*)&C3[2*lane];
        uint vp = v[dst*64 + lane];
        float base0 = lo2f(vp) + b2.x;
        float base1 = hi2f(vp) + b2.y;
        const char* ub = (const char*)u + 4*lane;
        float h0=0.f,h1=0.f,e0a=0.f,e1a=0.f;
        for (int j0=0; j0<n; j0+=64){
            int m = n - j0; if (m > 64) m = 64;
            int rx = 0, ry = 0;
            if (lane < m){ int2 rc = csr2[r0+j0+lane]; rx = rc.x; ry = rc.y; }
#pragma unroll 4
            for (int j=0;j<m;j++){
                int off = __builtin_amdgcn_readlane(rx, j);
                float d  = __uint_as_float((unsigned)__builtin_amdgcn_readlane(ry, j));
                uint up = *(const uint*)(ub + off);
                float a0 = fmaf(d, wd.x, base0 + lo2f(up));
                float a1 = fmaf(d, wd.y, base1 + hi2f(up));
                float s0 = sigf(a0), s1 = sigf(a1);
                float p0 = a0*s0, p1 = a1*s1;
                h0 += p0; h1 += p1;
                e0a = fmaf(s0, 1.f + a0 - p0, e0a);
                e1a = fmaf(s1, 1.f + a1 - p1, e1a);
            }
        }
        Gd[dst*64+lane] = pack2(ck.x*e0a, ck.y*e1a);
        float px = waveRed(ck.x*h0 + ck.y*h1);
        if (lane==0) x3[dst] = px + (float)n*D3[0];
    } else {
        int s = (blockIdx.x - NATOMS/4)*4 + wid;
        int doff = 0, dbit = 0;
        if (lane < 16){
            doff = gei[EGNN + s*16 + lane] << 8;
            dbit = __float_as_int(dgnn[s*16+lane]);
        }
        float2 wd = *(const float2*)&wdp[2*lane];
        float2 b2 = *(const float2*)&B3[2*lane];
        float2 ck = *(const float2*)&C3[2*lane];
        uint up = u[s*64 + lane];
        float us0 = lo2f(up) + b2.x;
        float us1 = hi2f(up) + b2.y;
        float cw0 = ck.x*wd.x, cw1 = ck.y*wd.y;
        float gs0=0.f, gs1=0.f;
        float A[16];
#pragma unroll
        for (int t=0;t<16;t++){
            int off = __builtin_amdgcn_readlane(doff, t);
            float d = __uint_as_float((unsigned)__builtin_amdgcn_readlane(dbit, t));
            uint vp = *(const uint*)((const char*)v + off + 4*lane);
            float a0 = fmaf(d, wd.x, us0 + lo2f(vp));
            float a1 = fmaf(d, wd.y, us1 + hi2f(vp));
            float s0 = sigf(a0), s1 = sigf(a1);
            float p0 = a0*s0, p1 = a1*s1;
            float dv0 = s0*(1.f + a0 - p0);
            float dv1 = s1*(1.f + a1 - p1);
            gs0 += dv0; gs1 += dv1;
            A[t] = fmaf(dv1, cw1, dv0*cw0);
        }
        Gs[s*64+lane] = pack2(ck.x*gs0, ck.y*gs1);
        float tot = red16(A, lane);   // lane l holds edge (l>>1)&15
        if (lane < 32 && !(lane & 1)) gdg[s*16 + (lane>>1)] = tot;
    }
}

// backward src pass for layer 2 / layer 1: recompute dv, multiply by gH[dst]
__global__ __launch_bounds__(256,4) void k_bwd_src(
    const int* __restrict__ gei, const float* __restrict__ dgnn,
    const uint* __restrict__ u, const uint* __restrict__ v,
    const float* __restrict__ wdp, const float* __restrict__ bb,
    const uint* __restrict__ gH,
    uint* __restrict__ Gs, float* __restrict__ gdg)
{
    int lane = threadIdx.x & 63, wid = threadIdx.x >> 6;
    int s = blockIdx.x*4 + wid;
    int doff = 0, dbit = 0;
    if (lane < 16){
        doff = gei[EGNN + s*16 + lane] << 8;
        dbit = __float_as_int(dgnn[s*16+lane]);
    }
    float gold = gdg[s*16 + ((lane>>1)&15)];
    float2 wd = *(const float2*)&wdp[2*lane];
    float2 b2 = *(const float2*)&bb[2*lane];
    uint up = u[s*64 + lane];
    float us0 = lo2f(up) + b2.x;
    float us1 = hi2f(up) + b2.y;
    float gs0=0.f, gs1=0.f;
    float A[16];
#pragma unroll
    for (int t=0;t<16;t++){
        int off = __builtin_amdgcn_readlane(doff, t);
        float d = __uint_as_float((unsigned)__builtin_amdgcn_readlane(dbit, t));
        uint vp = *(const uint*)((const char*)v + off + 4*lane);
        uint gp = *(const uint*)((const char*)gH + off + 4*lane);
        float a0 = fmaf(d, wd.x, us0 + lo2f(vp));
        float a1 = fmaf(d, wd.y, us1 + hi2f(vp));
        float s0 = sigf(a0), s1 = sigf(a1);
        float p0 = a0*s0, p1 = a1*s1;
        float ga0 = s0*(1.f + a0 - p0) * lo2f(gp);
        float ga1 = s1*(1.f + a1 - p1) * hi2f(gp);
        gs0 += ga0; gs1 += ga1;
        A[t] = fmaf(ga1, wd.y, ga0*wd.x);
    }
    if (Gs) Gs[s*64+lane] = pack2(gs0, gs1);
    float tot = red16(A, lane);
    if (lane < 32 && !(lane & 1)) gdg[s*16 + (lane>>1)] = gold + tot;
}

// MFMA node backward. If Sds != nullptr: Gd frag = gHin ⊙ Sds.
__global__ __launch_bounds__(256) void k_gx_node_bwd_mfma(
    const short* __restrict__ Gs, const short* __restrict__ Gd,
    const short* __restrict__ gHin, const short* __restrict__ Sds,
    const short* __restrict__ Ra, const short* __restrict__ Rb,
    const bf* __restrict__ dsz, const short* __restrict__ Rc,
    bf* __restrict__ gHout)
{
    __shared__ short st[64*HID];
    int lane = threadIdx.x & 63, w = threadIdx.x >> 6;
    int m0 = blockIdx.x*64 + w*16;
    int ar = lane & 15, kg = lane >> 4;
    bf8v as_[4], ad_[4];
#pragma unroll
    for (int s=0;s<4;s++)
        as_[s] = *(const bf8v*)&Gs[(size_t)(m0+ar)*HID + s*32 + kg*8];
    if (Sds){
#pragma unroll
        for (int s=0;s<4;s++){
            bf8v g = *(const bf8v*)&gHin[(size_t)(m0+ar)*HID + s*32 + kg*8];
            bf8v sd = *(const bf8v*)&Sds[(size_t)(m0+ar)*HID + s*32 + kg*8];
            bf8v r;
#pragma unroll
            for (int i=0;i<8;i++) r[i] = f2s(s2f(g[i])*s2f(sd[i]));
            ad_[s] = r;
        }
    } else {
#pragma unroll
        for (int s=0;s<4;s++)
            ad_[s] = *(const bf8v*)&Gd[(size_t)(m0+ar)*HID + s*32 + kg*8];
    }
    f4v acc[8];
#pragma unroll
    for (int nt=0;nt<8;nt++){
        acc[nt] = (f4v){0.f,0.f,0.f,0.f};
        const short* bpa = Ra + (nt*16+ar)*HID + kg*8;
        const short* bpb = Rb + (nt*16+ar)*HID + kg*8;
#pragma unroll
        for (int s=0;s<4;s++){
            bf8v ba = *(const bf8v*)(bpa + s*32);
            bf8v bb = *(const bf8v*)(bpb + s*32);
            acc[nt] = __builtin_amdgcn_mfma_f32_16x16x32_bf16(as_[s], ba, acc[nt], 0,0,0);
            acc[nt] = __builtin_amdgcn_mfma_f32_16x16x32_bf16(ad_[s], bb, acc[nt], 0,0,0);
        }
    }
#pragma unroll
    for (int nt=0;nt<8;nt++){
        int j = nt*16 + ar;
#pragma unroll
        for (int r=0;r<4;r++){
            int m = m0 + kg*4 + r;
            float t = acc[nt][r] * b2f(dsz[(size_t)m*HID + j]);
            st[(w*16 + kg*4 + r)*HID + j] = f2s(t);
        }
    }
    __syncthreads();
    bf8v af[4];
#pragma unroll
    for (int s=0;s<4;s++) af[s] = *(const bf8v*)&st[(w*16+ar)*HID + s*32 + kg*8];
    f4v a2[8];
#pragma unroll
    for (int nt=0;nt<8;nt++){
        a2[nt] = (f4v){0.f,0.f,0.f,0.f};
        const short* bp = Rc + (nt*16+ar)*HID + kg*8;
#pragma unroll
        for (int s=0;s<4;s++){
            bf8v bc = *(const bf8v*)(bp + s*32);
            a2[nt] = __builtin_amdgcn_mfma_f32_16x16x32_bf16(af[s], bc, a2[nt], 0,0,0);
        }
    }
#pragma unroll
    for (int nt=0;nt<8;nt++){
        int j = nt*16 + ar;
#pragma unroll
        for (int r=0;r<4;r++){
            gHout[(size_t)(m0 + kg*4 + r)*HID + j] = f2b(a2[nt][r]);
        }
    }
}

// ============ fused outputs: forces + per-molecule energies ============
__global__ __launch_bounds__(256) void k_out(
    const float* __restrict__ pos, const int* __restrict__ gei,
    const int* __restrict__ csr, const int* __restrict__ rptr, const int* __restrict__ cnt,
    const float* __restrict__ dgnn, const float* __restrict__ gdg,
    const float* __restrict__ grad,
    const float* __restrict__ egb, const float* __restrict__ x3,
    float* __restrict__ out)
{
    int tid = threadIdx.x;
    if (blockIdx.x < 512){
        float* fout = out + MOLS;
        int T = blockIdx.x*256 + tid;
        int i = T >> 3, p = T & 7;
        float px = pos[3*i+0], py = pos[3*i+1], pz = pos[3*i+2];
        float ax=0.f, ay=0.f, az=0.f;
        for (int j=p;j<16;j+=8){
            int e = i*16 + j;
            int o = gei[EGNN+e];
            float c = gdg[e]*frcp(dgnn[e]);
            ax += c*(px - pos[3*o+0]);
            ay += c*(py - pos[3*o+1]);
            az += c*(pz - pos[3*o+2]);
        }
        int n = cnt[i], r0 = rptr[i];
        for (int j=p;j<n;j+=8){
            int e = csr[r0+j];
            int o = e >> 4;
            float c = gdg[e]*frcp(dgnn[e]);
            ax += c*(px - pos[3*o+0]);
            ay += c*(py - pos[3*o+1]);
            az += c*(pz - pos[3*o+2]);
        }
        ax += __shfl_xor(ax,1); ax += __shfl_xor(ax,2); ax += __shfl_xor(ax,4);
        ay += __shfl_xor(ay,1); ay += __shfl_xor(ay,2); ay += __shfl_xor(ay,4);
        az += __shfl_xor(az,1); az += __shfl_xor(az,2); az += __shfl_xor(az,4);
        if (p==0){
            fout[3*i+0] = -(grad[3*i+0] + ax);
            fout[3*i+1] = -(grad[3*i+1] + ay);
            fout[3*i+2] = -(grad[3*i+2] + az);
        }
    } else {
        __shared__ float red[4];
        int m = blockIdx.x - 512;
        int i = m*ATOMSM + tid;
        float en = egb[i] + x3[i];
        float v = waveRed(en);
        int wave = tid>>6, lane = tid&63;
        if (lane==0) red[wave] = v;
        __syncthreads();
        if (tid==0) out[m] = red[0]+red[1]+red[2]+red[3];
    }
}

extern "C" void kernel_launch(void* const* d_in, const int* in_sizes, int n_in,
                              void* d_out, int out_size, void* d_ws, size_t ws_size,
                              hipStream_t stream)
{
    const float* pos  = (const float*)d_in[0];
    const float* feat = (const float*)d_in[1];
    const int* ei  = (const int*)d_in[3];
    const int* gei = (const int*)d_in[4];
    const float* A1f = (const float*)d_in[5];  const float* B1f = (const float*)d_in[6];
    const float* C1f = (const float*)d_in[7];  const float* D1f = (const float*)d_in[8];
    const float* A2f = (const float*)d_in[9];  const float* B2f = (const float*)d_in[10];
    const float* C2f = (const float*)d_in[11]; const float* D2f = (const float*)d_in[12];
    const float* A3f = (const float*)d_in[13]; const float* B3f = (const float*)d_in[14];
    const float* C3f = (const float*)d_in[15]; const float* D3f = (const float*)d_in[16];

    float* w = (float*)d_ws;
    size_t off = 0;
    auto nxt = [&](size_t n)->float*{ float* p = w + off; off += (n + 255) & ~(size_t)255; return p; };
    // contiguous zero-init region: Isum | cnt | grad  (5*NATOMS floats)
    float* Isum = nxt(NATOMS);
    int*   cnt  = (int*)nxt(NATOMS);
    float* grad = nxt(3*NATOMS);
    float* Bv = nxt(NATOMS); float* cB = nxt(NATOMS);
    float* gB = nxt(NATOMS); float* egb = nxt(NATOMS); float* x3 = nxt(NATOMS);
    int*   rptr = (int*)nxt(NATOMS);
    int*   csr  = (int*)nxt(EGNN);
    int2*  csr2 = (int2*)nxt((size_t)EGNN*2);
    float* dgnn = nxt(EGNN); float* gdgnn = nxt(EGNN); float* gdgb = nxt(EGB);
    bf* dsz1 = (bf*)nxt(NH/2); bf* dsz2 = (bf*)nxt(NH/2);
    bf* Hs1 = (bf*)nxt(NH/2); bf* Hs2 = (bf*)nxt(NH/2);
    bf* Gs3 = (bf*)nxt(NH/2); bf* Gd3 = (bf*)nxt(NH/2);
    bf* Sds2 = (bf*)nxt(NH/2);
    bf* u1 = (bf*)nxt(NH/2); bf* v1 = (bf*)nxt(NH/2);
    bf* u2 = (bf*)nxt(NH/2); bf* v2 = (bf*)nxt(NH/2);
    bf* v3 = (bf*)nxt(NH/2);
    short* C1t  = (short*)nxt(8192); short* C2t  = (short*)nxt(8192);
    short* A2at = (short*)nxt(8192); short* A2bt = (short*)nxt(8192);
    short* A3at = (short*)nxt(8192); short* A3bt = (short*)nxt(8192);
    short* rA2a = (short*)nxt(8192); short* rA2b = (short*)nxt(8192);
    short* rA3a = (short*)nxt(8192); short* rA3b = (short*)nxt(8192);
    short* rC1  = (short*)nxt(8192); short* rC2  = (short*)nxt(8192);
    // aliases:
    bf* u3  = Hs1;      // Hs1 dead after node_fwd #1
    bf* gH2 = Hs2;      // Hs2 dead after node_fwd #2
    bf* Gs2 = Gs3;      // dead after gx_node_bwd(3->2)
    bf* gH1 = u3;       // u3 dead after l3 kernel

    // single combined zero-init (Isum|cnt|grad are contiguous)
    hipMemsetAsync(Isum, 0, (size_t)5*NATOMS*sizeof(float), stream);

    // MEGA-A: weights + uv1 + gbA + dist
    k_A<<<64 + NH/512 + 512 + EGNN/256, 256, 0, stream>>>(
        A2f, C1f, A3f, C2f,
        C1t, C2t, A2at, A2bt, A3at, A3bt, rA2a, rA2b, rA3a, rA3b, rC1, rC2,
        feat, A1f, u1, v1,
        pos, ei, Isum, gei, dgnn, cnt);

    // MEGA-B: gbB + scan + fill (LDS cursors)
    k_B<<<128,256,0,stream>>>(feat, Isum, Bv, cB, gB, egb, cnt, rptr,
                              gei, dgnn, csr, csr2);

    // fused: gbC + layer-1 edge forward (independent; co-scheduled waves)
    k_ef0C<<<512 + NATOMS/4, 256, 0, stream>>>(
        pos, feat, ei, Bv, egb, gdgb, gB,
        csr2, rptr, cnt, (const uint*)u1, (const uint*)v1, A1f+4*HID, B1f, (uint*)Hs1);

    // fused: gbE + layer-1 node MFMA (independent)
    k_nf1E<<<512 + NATOMS/64, 256, 0, stream>>>(
        pos, feat, ei, cB, gB, gdgb, grad,
        (const short*)Hs1, cnt, C1t, D1f, A2at, A2bt, dsz1, u2, v2);

    // forward layer 2
    k_edge_fwd1<<<NATOMS/4,256,0,stream>>>(csr2, rptr, cnt, (const uint*)u2, (const uint*)v2,
                                           A2f+256*HID, B2f, (uint*)Hs2, (uint*)Sds2);
    k_node_fwd_uv_mfma<<<NATOMS/64,256,0,stream>>>((const short*)Hs2, cnt, C2t, D2f,
                                                   A3at, A3bt, dsz2, u3, v3);

    // layer-3 fused dst+src (wave-per-node)
    k_l3<<<2*(NATOMS/4),256,0,stream>>>(csr2, rptr, cnt, gei, dgnn,
                                        (const uint*)u3, (const uint*)v3,
                                        A3f, B3f, C3f, D3f,
                                        (uint*)Gd3, x3, (uint*)Gs3, gdgnn);

    // backward chain
    k_gx_node_bwd_mfma<<<NATOMS/64,256,0,stream>>>((const short*)Gs3, (const short*)Gd3,
        (const short*)nullptr, (const short*)nullptr, rA3a, rA3b, dsz2, rC2, gH2);
    k_bwd_src<<<NATOMS/4,256,0,stream>>>(gei, dgnn, (const uint*)u2, (const uint*)v2,
                                         A2f+256*HID, B2f, (const uint*)gH2,
                                         (uint*)Gs2, gdgnn);
    k_gx_node_bwd_mfma<<<NATOMS/64,256,0,stream>>>((const short*)Gs2, (const short*)nullptr,
        (const short*)gH2, (const short*)Sds2, rA2a, rA2b, dsz1, rC1, gH1);
    k_bwd_src<<<NATOMS/4,256,0,stream>>>(gei, dgnn, (const uint*)u1, (const uint*)v1,
                                         A1f+4*HID, B1f, (const uint*)gH1,
                                         (uint*)nullptr, gdgnn);

    // fused outputs (forces + energies)
    k_out<<<576,256,0,stream>>>(pos, gei, csr, rptr, cnt, dgnn, gdgnn,
                                grad, egb, x3, (float*)d_out);
}